// Round 3
// baseline (21182.457 us; speedup 1.0000x reference)
//
#include <hip/hip_runtime.h>
#include <hip/hip_bf16.h>

typedef _Float16 f16_t;
using f16x8  = __attribute__((ext_vector_type(8))) _Float16;
using f32x4  = __attribute__((ext_vector_type(4))) float;
using f32x16 = __attribute__((ext_vector_type(16))) float;
using u64    = unsigned long long;
using u64x2  = __attribute__((ext_vector_type(2))) unsigned long long;

#define L_DIM 512
#define B_DIM 64
#define C_DIM 512
#define H_DIM 1024
#define MROWS (L_DIM * B_DIM) /* 32768 */

// ---------------- f32 -> f16 convert ----------------
__global__ void cvt_kernel(const float* __restrict__ src, f16_t* __restrict__ dst, int n8) {
  int i = blockIdx.x * blockDim.x + threadIdx.x;
  if (i >= n8) return;
  const float4* s4 = reinterpret_cast<const float4*>(src) + (size_t)i * 2;
  float4 a = s4[0], b = s4[1];
  f16x8 o;
  o[0] = (f16_t)a.x; o[1] = (f16_t)a.y; o[2] = (f16_t)a.z; o[3] = (f16_t)a.w;
  o[4] = (f16_t)b.x; o[5] = (f16_t)b.y; o[6] = (f16_t)b.z; o[7] = (f16_t)b.w;
  reinterpret_cast<f16x8*>(dst)[i] = o;
}

// ---------------- async global->LDS 16B ----------------
__device__ inline void gload_lds16(const void* g, void* l) {
  __builtin_amdgcn_global_load_lds(
      (const __attribute__((address_space(1))) unsigned int*)g,
      (__attribute__((address_space(3))) unsigned int*)l, 16, 0, 0);
}

// ---------------- bt-GEMM: C[M,N] = A[M,K] @ B[N,K]^T + bias ----------------
#define TM 128
#define TN 128
#define BKK 64
__global__ __launch_bounds__(256) void gemm_bt_bias(
    const f16_t* __restrict__ A, const f16_t* __restrict__ B,
    const float* __restrict__ bias, float* __restrict__ C,
    int M, int N, int K) {
  __shared__ f16_t As[TM * BKK];
  __shared__ f16_t Bs[TN * BKK];
  const int tid = threadIdx.x;
  const int w = tid >> 6, l = tid & 63;
  const int nbn = N / TN;
  const int bm = blockIdx.x / nbn, bn = blockIdx.x % nbn;
  const int m0 = bm * TM, n0 = bn * TN;
  const int wr = w >> 1, wc = w & 1;
  const int lr = l & 15;
  const int lk = (l >> 4) * 8;
  f32x4 acc[4][4] = {};

  for (int kt = 0; kt < K; kt += BKK) {
#pragma unroll
    for (int r = 0; r < 4; ++r) {
      int p8 = r * 256 + tid;
      int row = p8 >> 3, col = (p8 & 7) * 8;
      gload_lds16(A + (size_t)(m0 + row) * K + kt + col, &As[(size_t)(r * 256 + w * 64) * 8]);
    }
#pragma unroll
    for (int r = 0; r < 4; ++r) {
      int p8 = r * 256 + tid;
      int row = p8 >> 3, col = (p8 & 7) * 8;
      gload_lds16(B + (size_t)(n0 + row) * K + kt + col, &Bs[(size_t)(r * 256 + w * 64) * 8]);
    }
    __syncthreads();
#pragma unroll
    for (int kk = 0; kk < 2; ++kk) {
      f16x8 af[4], bfr[4];
#pragma unroll
      for (int i = 0; i < 4; ++i)
        af[i] = *reinterpret_cast<const f16x8*>(&As[(wr * 64 + i * 16 + lr) * BKK + kk * 32 + lk]);
#pragma unroll
      for (int j = 0; j < 4; ++j)
        bfr[j] = *reinterpret_cast<const f16x8*>(&Bs[(wc * 64 + j * 16 + lr) * BKK + kk * 32 + lk]);
#pragma unroll
      for (int i = 0; i < 4; ++i)
#pragma unroll
        for (int j = 0; j < 4; ++j)
          acc[i][j] = __builtin_amdgcn_mfma_f32_16x16x32_f16(af[i], bfr[j], acc[i][j], 0, 0, 0);
    }
    __syncthreads();
  }
  const int crow = (l >> 4) * 4, ccol = l & 15;
#pragma unroll
  for (int j = 0; j < 4; ++j) {
    int col = n0 + wc * 64 + j * 16 + ccol;
    float bv = bias[col];
#pragma unroll
    for (int i = 0; i < 4; ++i) {
      int rowb = m0 + wr * 64 + i * 16 + crow;
#pragma unroll
      for (int r = 0; r < 4; ++r)
        C[(size_t)(rowb + r) * N + col] = acc[i][j][r] + bv;
    }
  }
}

// ---------------- persistent-scan inter-block barrier (flags padded 128B) ----------------
__device__ inline void scan_barrier(unsigned* flags, int g, unsigned target, int tid) {
  __syncthreads();  // drains vmcnt -> prior agent-scope stores complete at coherence point
  if (tid < 64) {
    if (tid == 0)
      __hip_atomic_store(&flags[g * 32], target, __ATOMIC_RELAXED, __HIP_MEMORY_SCOPE_AGENT);
    int src = (tid & 15) * 32;
    while (true) {
      unsigned v = __hip_atomic_load(&flags[src], __ATOMIC_RELAXED, __HIP_MEMORY_SCOPE_AGENT);
      if (__all((int)(v >= target))) break;
    }
  }
  __syncthreads();
}

// ---------------- recurrent scan: h = tanh(xp_t + h @ W^T) ----------------
// 16 blocks x 256 threads. Block g owns output cols [g*64, g*64+64).
// W slice (64 rows x 1024) resident in LDS (XOR swizzled, 0 bank conflicts measured).
// h ping-pongs in global ws as f16 via agent-scope atomics; per step each thread
// issues ALL 128 h-loads up front (256 VGPRs live, 1 wave/SIMD) -> one latency hit.
__global__ __launch_bounds__(256, 1) void rnn_scan(
    const float* __restrict__ xp,     // [512][64][1024] f32
    const f16_t* __restrict__ Wr,     // [1024][1024] f16 (W_hh)
    const float* __restrict__ h0in,   // [64][1024] f32 initial state
    f16_t* __restrict__ hbuf,         // 2 x 64*1024 f16 ping-pong
    unsigned* __restrict__ flags,     // 16 flags, stride 32 u32 (128B lines)
    f16_t* __restrict__ out_h,        // [512][64][1024] f16 or null
    float* __restrict__ out_f,        // [512][64][1024] f32 or null
    float* __restrict__ state_out) {  // [64][1024] f32 final h
  extern __shared__ char smem[];      // [0,131072) W swizzled; [131072,139264) f16 pack
  unsigned short* pk = reinterpret_cast<unsigned short*>(smem + 131072);
  const int tid = threadIdx.x, g = blockIdx.x;
  const int w = tid >> 6, l = tid & 63;
  const int n0 = g * 64;
  const int wr = w >> 1, wc = w & 1;
  const int la = l & 31, lb = l >> 5;

  // stage W slice (rows n0..n0+63, all K) into LDS with XOR swizzle on 16B granules
  for (int i = 0; i < 32; ++i) {
    int g8 = i * 256 + tid;           // [0, 8192)
    int row = g8 >> 7, cb = g8 & 127;
    f16x8 v = *reinterpret_cast<const f16x8*>(Wr + (size_t)(n0 + row) * H_DIM + cb * 8);
    *reinterpret_cast<f16x8*>(smem + row * 2048 + ((cb ^ (row & 31)) << 4)) = v;
  }
  // init ping h from input state (this block's column slice), agent-scope
  {
    unsigned* hp = reinterpret_cast<unsigned*>(hbuf);
    for (int i = 0; i < 8; ++i) {
      int idx = i * 256 + tid;        // [0, 2048) f16-pairs
      int row = idx >> 5, cp = idx & 31;
      int col = n0 + cp * 2;
      float f0 = h0in[row * H_DIM + col];
      float f1 = h0in[row * H_DIM + col + 1];
      unsigned short u0 = __builtin_bit_cast(unsigned short, (f16_t)f0);
      unsigned short u1 = __builtin_bit_cast(unsigned short, (f16_t)f1);
      unsigned pkv = (unsigned)u0 | ((unsigned)u1 << 16);
      __hip_atomic_store(&hp[(row * H_DIM + col) >> 1], pkv, __ATOMIC_RELAXED, __HIP_MEMORY_SCOPE_AGENT);
    }
  }
  scan_barrier(flags, g, 1u, tid);

  const int arow = wr * 32 + la;        // h row this lane reads (A operand)
  const int colg = n0 + wc * 32 + la;   // output col this lane owns
  const int rwrow = wc * 32 + la;       // W-slice row for B operand
  const char* smem_wrow = smem + rwrow * 2048;
  const int rx = rwrow & 31;
  const int srow = tid >> 2;            // store-phase: row 0..63
  const int soff = (tid & 3) * 32;      // store-phase: byte offset in 128B row-slice

  for (int t = 0; t < 512; ++t) {
    const char* hs = reinterpret_cast<const char*>(hbuf + (size_t)(t & 1) * (B_DIM * H_DIM));
    char* hd = reinterpret_cast<char*>(hbuf + (size_t)((t + 1) & 1) * (B_DIM * H_DIM));
    const char* hb = hs + arow * 2048 + lb * 16;

    // issue ALL h loads first (deep pipeline, one latency exposure)
    u64 p[128];
#pragma unroll
    for (int k = 0; k < 64; ++k) {
      p[2 * k]     = __hip_atomic_load((const u64*)(hb + k * 32),     __ATOMIC_RELAXED, __HIP_MEMORY_SCOPE_AGENT);
      p[2 * k + 1] = __hip_atomic_load((const u64*)(hb + k * 32 + 8), __ATOMIC_RELAXED, __HIP_MEMORY_SCOPE_AGENT);
    }
    // then xp loads (latency hidden under h-load wait + MFMA)
    float xv[16];
#pragma unroll
    for (int r = 0; r < 16; ++r) {
      int row = wr * 32 + (r & 3) + 8 * (r >> 2) + 4 * lb;
      xv[r] = xp[(size_t)t * (B_DIM * H_DIM) + row * H_DIM + colg];
    }
    __builtin_amdgcn_sched_barrier(0);  // pin: no sinking loads into MFMA loop

    f32x16 acc = {};
#pragma unroll
    for (int kc = 0; kc < 64; ++kc) {
      int cb = (kc * 2 + lb) ^ rx;
      f16x8 bfr = *reinterpret_cast<const f16x8*>(smem_wrow + (cb << 4));
      u64x2 aa; aa[0] = p[2 * kc]; aa[1] = p[2 * kc + 1];
      f16x8 af = __builtin_bit_cast(f16x8, aa);
      acc = __builtin_amdgcn_mfma_f32_32x32x16_f16(af, bfr, acc, 0, 0, 0);
    }

    const bool wlast = (t == 511);
#pragma unroll
    for (int r = 0; r < 16; ++r) {
      int row = wr * 32 + (r & 3) + 8 * (r >> 2) + 4 * lb;
      float z = acc[r] + xv[r];
      z = fminf(fmaxf(z, -15.f), 15.f);
      float e = __expf(2.f * z);
      float h = 1.f - __fdividef(2.f, e + 1.f);
      f16_t hf = (f16_t)h;
      pk[row * 64 + (wc * 32 + la)] = __builtin_bit_cast(unsigned short, hf);
      if (wlast) state_out[row * H_DIM + colg] = (float)hf;
    }
    __syncthreads();  // pack visible to all threads

    u64x2 q0 = *reinterpret_cast<const u64x2*>(reinterpret_cast<const char*>(pk) + tid * 32);
    u64x2 q1 = *reinterpret_cast<const u64x2*>(reinterpret_cast<const char*>(pk) + tid * 32 + 16);
    {
      char* hda = hd + srow * 2048 + n0 * 2 + soff;
      __hip_atomic_store((u64*)(hda),      q0[0], __ATOMIC_RELAXED, __HIP_MEMORY_SCOPE_AGENT);
      __hip_atomic_store((u64*)(hda + 8),  q0[1], __ATOMIC_RELAXED, __HIP_MEMORY_SCOPE_AGENT);
      __hip_atomic_store((u64*)(hda + 16), q1[0], __ATOMIC_RELAXED, __HIP_MEMORY_SCOPE_AGENT);
      __hip_atomic_store((u64*)(hda + 24), q1[1], __ATOMIC_RELAXED, __HIP_MEMORY_SCOPE_AGENT);
    }
    if (out_h) {
      char* oa = (char*)out_h + (size_t)t * 131072 + srow * 2048 + n0 * 2 + soff;
      *reinterpret_cast<u64x2*>(oa) = q0;
      *reinterpret_cast<u64x2*>(oa + 16) = q1;
    }
    if (out_f) {
      f16x8 a0 = __builtin_bit_cast(f16x8, q0);
      f16x8 a1 = __builtin_bit_cast(f16x8, q1);
      float4 f0 = {(float)a0[0], (float)a0[1], (float)a0[2], (float)a0[3]};
      float4 f1 = {(float)a0[4], (float)a0[5], (float)a0[6], (float)a0[7]};
      float4 f2 = {(float)a1[0], (float)a1[1], (float)a1[2], (float)a1[3]};
      float4 f3 = {(float)a1[4], (float)a1[5], (float)a1[6], (float)a1[7]};
      char* oa = (char*)out_f + (size_t)t * 262144 + srow * 4096 + n0 * 4 + soff * 2;
      *reinterpret_cast<float4*>(oa)      = f0;
      *reinterpret_cast<float4*>(oa + 16) = f1;
      *reinterpret_cast<float4*>(oa + 32) = f2;
      *reinterpret_cast<float4*>(oa + 48) = f3;
    }
    if (!wlast) scan_barrier(flags, g, (unsigned)(t + 2), tid);
  }
}

extern "C" void kernel_launch(void* const* d_in, const int* in_sizes, int n_in,
                              void* d_out, int out_size, void* d_ws, size_t ws_size,
                              hipStream_t stream) {
  const float* x     = (const float*)d_in[0];
  const float* state = (const float*)d_in[1];
  const float* Wih0  = (const float*)d_in[2];
  const float* Whh0  = (const float*)d_in[3];
  const float* b0    = (const float*)d_in[4];
  const float* Wih1  = (const float*)d_in[5];
  const float* Whh1  = (const float*)d_in[6];
  const float* b1    = (const float*)d_in[7];
  float* out = (float*)d_out;

  char* ws = (char*)d_ws;
  unsigned* flags = (unsigned*)(ws + 0);               //   4 KiB (2 sets, 128B lines)
  f16_t* hbuf     = (f16_t*)(ws + 4096);               // 256 KiB ping-pong h
  f16_t* Wih0h    = (f16_t*)(ws + 266240);
  f16_t* Whh0h    = (f16_t*)(ws + 1314816);
  f16_t* Wih1h    = (f16_t*)(ws + 3411968);
  f16_t* Whh1h    = (f16_t*)(ws + 5509120);
  f16_t* xh       = (f16_t*)(ws + 7606272);            //  32 MiB x f16
  f16_t* out0     = (f16_t*)(ws + 41160704);           //  64 MiB layer0 outputs f16
  float* xp       = (float*)(ws + 108269568);          // 128 MiB input projections f32

  hipMemsetAsync(ws, 0, 4096, stream);
  cvt_kernel<<<8192, 256, 0, stream>>>(x,    xh,    16777216 / 8);
  cvt_kernel<<<256,  256, 0, stream>>>(Wih0, Wih0h,   524288 / 8);
  cvt_kernel<<<512,  256, 0, stream>>>(Whh0, Whh0h,  1048576 / 8);
  cvt_kernel<<<512,  256, 0, stream>>>(Wih1, Wih1h,  1048576 / 8);
  cvt_kernel<<<512,  256, 0, stream>>>(Whh1, Whh1h,  1048576 / 8);

  // layer 0 input projection: [32768,512] @ [1024,512]^T
  gemm_bt_bias<<<dim3((MROWS / TM) * (H_DIM / TN)), 256, 0, stream>>>(
      xh, Wih0h, b0, xp, MROWS, H_DIM, C_DIM);

  (void)hipFuncSetAttribute((const void*)rnn_scan,
                            hipFuncAttributeMaxDynamicSharedMemorySize, 139264);
  float* state_out = out + (size_t)L_DIM * B_DIM * H_DIM;  // 33554432
  rnn_scan<<<16, 256, 139264, stream>>>(xp, Whh0h, state, hbuf, flags,
                                        out0, nullptr, state_out);
  // layer 1 input projection: [32768,1024] @ [1024,1024]^T
  gemm_bt_bias<<<dim3((MROWS / TM) * (H_DIM / TN)), 256, 0, stream>>>(
      out0, Wih1h, b1, xp, MROWS, H_DIM, H_DIM);
  rnn_scan<<<16, 256, 139264, stream>>>(xp, Whh1h, state + B_DIM * H_DIM, hbuf, flags + 512,
                                        nullptr, out, state_out + B_DIM * H_DIM);
}

// Round 5
// 6883.498 us; speedup vs baseline: 3.0773x; 3.0773x over previous
//
#include <hip/hip_runtime.h>
#include <hip/hip_bf16.h>

typedef _Float16 f16_t;
using f16x8  = __attribute__((ext_vector_type(8))) _Float16;
using f32x4  = __attribute__((ext_vector_type(4))) float;
using f32x16 = __attribute__((ext_vector_type(16))) float;
using u64    = unsigned long long;
using u64x2  = __attribute__((ext_vector_type(2))) unsigned long long;

#define L_DIM 512
#define B_DIM 64
#define C_DIM 512
#define H_DIM 1024
#define MROWS (L_DIM * B_DIM) /* 32768 */

// ---------------- f32 -> f16 convert ----------------
__global__ void cvt_kernel(const float* __restrict__ src, f16_t* __restrict__ dst, int n8) {
  int i = blockIdx.x * blockDim.x + threadIdx.x;
  if (i >= n8) return;
  const float4* s4 = reinterpret_cast<const float4*>(src) + (size_t)i * 2;
  float4 a = s4[0], b = s4[1];
  f16x8 o;
  o[0] = (f16_t)a.x; o[1] = (f16_t)a.y; o[2] = (f16_t)a.z; o[3] = (f16_t)a.w;
  o[4] = (f16_t)b.x; o[5] = (f16_t)b.y; o[6] = (f16_t)b.z; o[7] = (f16_t)b.w;
  reinterpret_cast<f16x8*>(dst)[i] = o;
}

// ---------------- async global->LDS 16B ----------------
__device__ inline void gload_lds16(const void* g, void* l) {
  __builtin_amdgcn_global_load_lds(
      (const __attribute__((address_space(1))) unsigned int*)g,
      (__attribute__((address_space(3))) unsigned int*)l, 16, 0, 0);
}

// ---------------- bt-GEMM: C[M,N] = A[M,K] @ B[N,K]^T + bias ----------------
#define TM 128
#define TN 128
#define BKK 64
__global__ __launch_bounds__(256) void gemm_bt_bias(
    const f16_t* __restrict__ A, const f16_t* __restrict__ B,
    const float* __restrict__ bias, float* __restrict__ C,
    int M, int N, int K) {
  __shared__ f16_t As[TM * BKK];
  __shared__ f16_t Bs[TN * BKK];
  const int tid = threadIdx.x;
  const int w = tid >> 6, l = tid & 63;
  const int nbn = N / TN;
  const int bm = blockIdx.x / nbn, bn = blockIdx.x % nbn;
  const int m0 = bm * TM, n0 = bn * TN;
  const int wr = w >> 1, wc = w & 1;
  const int lr = l & 15;
  const int lk = (l >> 4) * 8;
  f32x4 acc[4][4] = {};

  for (int kt = 0; kt < K; kt += BKK) {
#pragma unroll
    for (int r = 0; r < 4; ++r) {
      int p8 = r * 256 + tid;
      int row = p8 >> 3, col = (p8 & 7) * 8;
      gload_lds16(A + (size_t)(m0 + row) * K + kt + col, &As[(size_t)(r * 256 + w * 64) * 8]);
    }
#pragma unroll
    for (int r = 0; r < 4; ++r) {
      int p8 = r * 256 + tid;
      int row = p8 >> 3, col = (p8 & 7) * 8;
      gload_lds16(B + (size_t)(n0 + row) * K + kt + col, &Bs[(size_t)(r * 256 + w * 64) * 8]);
    }
    __syncthreads();
#pragma unroll
    for (int kk = 0; kk < 2; ++kk) {
      f16x8 af[4], bfr[4];
#pragma unroll
      for (int i = 0; i < 4; ++i)
        af[i] = *reinterpret_cast<const f16x8*>(&As[(wr * 64 + i * 16 + lr) * BKK + kk * 32 + lk]);
#pragma unroll
      for (int j = 0; j < 4; ++j)
        bfr[j] = *reinterpret_cast<const f16x8*>(&Bs[(wc * 64 + j * 16 + lr) * BKK + kk * 32 + lk]);
#pragma unroll
      for (int i = 0; i < 4; ++i)
#pragma unroll
        for (int j = 0; j < 4; ++j)
          acc[i][j] = __builtin_amdgcn_mfma_f32_16x16x32_f16(af[i], bfr[j], acc[i][j], 0, 0, 0);
    }
    __syncthreads();
  }
  const int crow = (l >> 4) * 4, ccol = l & 15;
#pragma unroll
  for (int j = 0; j < 4; ++j) {
    int col = n0 + wc * 64 + j * 16 + ccol;
    float bv = bias[col];
#pragma unroll
    for (int i = 0; i < 4; ++i) {
      int rowb = m0 + wr * 64 + i * 16 + crow;
#pragma unroll
      for (int r = 0; r < 4; ++r)
        C[(size_t)(rowb + r) * N + col] = acc[i][j][r] + bv;
    }
  }
}

// ---------------- persistent-scan inter-block barrier ----------------
__device__ inline void scan_barrier(unsigned* flags, int g, unsigned target, int tid) {
  __syncthreads();
  if (tid < 64) {
    if (tid == 0)
      __hip_atomic_store(&flags[g], target, __ATOMIC_RELAXED, __HIP_MEMORY_SCOPE_AGENT);
    int src = tid & 15;
    while (true) {
      unsigned v = __hip_atomic_load(&flags[src], __ATOMIC_RELAXED, __HIP_MEMORY_SCOPE_AGENT);
      if (__all((int)(v >= target))) break;
    }
  }
  __syncthreads();
}

// 16B coherent load/store (sc0 sc1: bypass L1/L2, served at coherence point)
#define GLOAD16(dst, addr) \
  asm volatile("global_load_dwordx4 %0, %1, off sc0 sc1" : "=&v"(dst) : "v"(addr) : "memory")
#define GSTORE16(addr, val) \
  asm volatile("global_store_dwordx4 %0, %1, off sc0 sc1" :: "v"(addr), "v"(val) : "memory")
#define WAITV(n) do { asm volatile("s_waitcnt vmcnt(" #n ")" ::: "memory"); \
                      __builtin_amdgcn_sched_barrier(0); } while (0)
#define MFMA_CHUNK(buf, base, accv)                                           \
  _Pragma("unroll")                                                           \
  for (int i_ = 0; i_ < 16; ++i_) {                                           \
    int cbx_ = (((base) + i_) * 2 + lb) ^ rx;                                 \
    f16x8 bfr_ = *reinterpret_cast<const f16x8*>(smem_wrow + (cbx_ << 4));    \
    accv = __builtin_amdgcn_mfma_f32_32x32x16_f16(                            \
        __builtin_bit_cast(f16x8, buf[i_]), bfr_, accv, 0, 0, 0);             \
  }

// ---------------- recurrent scan: h = tanh(xp_t + h @ W^T) ----------------
// 16 blocks x 256 threads. Block g owns output cols [g*64, g*64+64).
// h ping-pong buffer in MFMA-A-FRAGMENT layout:
//   hbuf[t&1][kb][rh][lane][16B]; fragment(kb,rh,lane) =
//   h[row rh*32+(lane&31)][cols kb*16+(lane>>5)*8 ..+8]
// Reader wave: 64 coalesced dwordx4 coherent loads (1KB each), pipelined in
// 4 chunks of 16 with counted vmcnt waits (<=128 VGPR of buffers live).
__global__ __launch_bounds__(256, 1) void rnn_scan(
    const float* __restrict__ xp,     // [512][64][1024] f32
    const f16_t* __restrict__ Wr,     // [1024][1024] f16 (W_hh)
    const float* __restrict__ h0in,   // [64][1024] f32 initial state
    char* __restrict__ hbuf,          // 2 x 128KB fragment-layout ping-pong
    unsigned* __restrict__ flags,     // 16 flags (one line)
    f16_t* __restrict__ out_h,        // [512][64][1024] f16 or null
    float* __restrict__ out_f,        // [512][64][1024] f32 or null
    float* __restrict__ state_out) {  // [64][1024] f32 final h
  extern __shared__ char smem[];      // [0,131072) W swizzled; [131072,139264) pk pack
  char* pkc = smem + 131072;          // 64 rows x 128B, granule-swizzled
  const int tid = threadIdx.x, g = blockIdx.x;
  const int w = tid >> 6, l = tid & 63;
  const int n0 = g * 64;
  const int wr = w >> 1, wc = w & 1;
  const int la = l & 31, lb = l >> 5;

  // stage W slice (rows n0..n0+63, all K) into LDS with XOR swizzle on 16B granules
  for (int i = 0; i < 32; ++i) {
    int g8 = i * 256 + tid;
    int row = g8 >> 7, cb = g8 & 127;
    f16x8 v = *reinterpret_cast<const f16x8*>(Wr + (size_t)(n0 + row) * H_DIM + cb * 8);
    *reinterpret_cast<f16x8*>(smem + row * 2048 + ((cb ^ (row & 31)) << 4)) = v;
  }
  // init ping fragments (this block's 4 kb chunks) from f32 state
#pragma unroll
  for (int i = 0; i < 2; ++i) {
    int f = tid * 2 + i;                    // [0,512)
    int kbl = f >> 7, rem = f & 127, rh = rem >> 6, lf = rem & 63;
    int row = rh * 32 + (lf & 31);
    int cgl = (4 * g + kbl) * 16 + (lf >> 5) * 8;
    const float* s = h0in + row * H_DIM + cgl;
    float4 a = *reinterpret_cast<const float4*>(s);
    float4 b = *reinterpret_cast<const float4*>(s + 4);
    f16x8 v;
    v[0] = (f16_t)a.x; v[1] = (f16_t)a.y; v[2] = (f16_t)a.z; v[3] = (f16_t)a.w;
    v[4] = (f16_t)b.x; v[5] = (f16_t)b.y; v[6] = (f16_t)b.z; v[7] = (f16_t)b.w;
    GSTORE16(hbuf + g * 8192 + f * 16, v);
  }
  asm volatile("s_waitcnt vmcnt(0)" ::: "memory");
  scan_barrier(flags, g, 1u, tid);

  const int colg = n0 + wc * 32 + la;   // output col this lane owns
  const int rwrow = wc * 32 + la;       // W-slice row for B operand
  const char* smem_wrow = smem + rwrow * 2048;
  const int rx = rwrow & 31;
  const int pcg = (wc * 32 + la) >> 3;  // pk granule of this lane's col
  const int pco = ((wc * 32 + la) & 7) * 2;

  for (int t = 0; t < 512; ++t) {
    const char* hs = hbuf + (size_t)(t & 1) * 131072;
    char* hd = hbuf + (size_t)((t + 1) & 1) * 131072;
    const char* hb = hs + wr * 1024 + l * 16;

    u64x2 bf0[16], bf1[16];
    // chunk0 (kb 0..15)
#pragma unroll
    for (int i = 0; i < 16; ++i) GLOAD16(bf0[i], hb + i * 2048);
    // xp loads (plain cached; completion guaranteed by later waits / compiler)
    float xv[16];
#pragma unroll
    for (int r = 0; r < 16; ++r) {
      int row = wr * 32 + (r & 3) + 8 * (r >> 2) + 4 * lb;
      xv[r] = xp[(size_t)t * (B_DIM * H_DIM) + row * H_DIM + colg];
    }
    // chunk1 (kb 16..31)
#pragma unroll
    for (int i = 0; i < 16; ++i) GLOAD16(bf1[i], hb + (16 + i) * 2048);

    f32x16 acc0 = {}, acc1 = {};
    WAITV(32);                 // chunk0 complete (48 issued, keep newest 32)
    MFMA_CHUNK(bf0, 0, acc0);
#pragma unroll
    for (int i = 0; i < 16; ++i) GLOAD16(bf0[i], hb + (32 + i) * 2048);
    WAITV(16);                 // chunk1 complete (64 issued, keep newest 16)
    MFMA_CHUNK(bf1, 16, acc1);
#pragma unroll
    for (int i = 0; i < 16; ++i) GLOAD16(bf1[i], hb + (48 + i) * 2048);
    WAITV(16);                 // chunk2 complete (80 issued, keep newest 16)
    MFMA_CHUNK(bf0, 32, acc0);
    WAITV(0);                  // chunk3 complete
    MFMA_CHUNK(bf1, 48, acc1);

    const bool wlast = (t == 511);
#pragma unroll
    for (int r = 0; r < 16; ++r) {
      int row = wr * 32 + (r & 3) + 8 * (r >> 2) + 4 * lb;
      float z = (acc0[r] + acc1[r]) + xv[r];
      z = fminf(fmaxf(z, -15.f), 15.f);
      float e = __expf(2.f * z);
      float h = 1.f - __fdividef(2.f, e + 1.f);
      f16_t hf = (f16_t)h;
      *reinterpret_cast<unsigned short*>(
          pkc + row * 128 + ((pcg ^ (row & 7)) << 4) + pco) =
          __builtin_bit_cast(unsigned short, hf);
      if (wlast) state_out[row * H_DIM + colg] = (float)hf;
    }
    __syncthreads();  // pack visible block-wide

    // write this block's 8KB fragment slice, coalesced coherent stores
#pragma unroll
    for (int i = 0; i < 2; ++i) {
      int f = tid * 2 + i;
      int kbl = f >> 7, rem = f & 127, rh = rem >> 6, lf = rem & 63;
      int row = rh * 32 + (lf & 31);
      int cg = kbl * 2 + (lf >> 5);
      u64x2 q = *reinterpret_cast<const u64x2*>(pkc + row * 128 + ((cg ^ (row & 7)) << 4));
      GSTORE16(hd + g * 8192 + f * 16, q);
    }

    // sequence outputs (row-major), via unswizzled pk read
    {
      const int srow = tid >> 2;
      const int cg0 = (tid & 3) * 2;
      u64x2 q0 = *reinterpret_cast<const u64x2*>(pkc + srow * 128 + ((cg0 ^ (srow & 7)) << 4));
      u64x2 q1 = *reinterpret_cast<const u64x2*>(pkc + srow * 128 + (((cg0 + 1) ^ (srow & 7)) << 4));
      const int soff = (tid & 3) * 32;
      if (out_h) {
        char* oa = (char*)out_h + (size_t)t * 131072 + srow * 2048 + n0 * 2 + soff;
        *reinterpret_cast<u64x2*>(oa) = q0;
        *reinterpret_cast<u64x2*>(oa + 16) = q1;
      }
      if (out_f) {
        f16x8 a0 = __builtin_bit_cast(f16x8, q0);
        f16x8 a1 = __builtin_bit_cast(f16x8, q1);
        float4 f0 = {(float)a0[0], (float)a0[1], (float)a0[2], (float)a0[3]};
        float4 f1 = {(float)a0[4], (float)a0[5], (float)a0[6], (float)a0[7]};
        float4 f2 = {(float)a1[0], (float)a1[1], (float)a1[2], (float)a1[3]};
        float4 f3 = {(float)a1[4], (float)a1[5], (float)a1[6], (float)a1[7]};
        char* oa = (char*)out_f + (size_t)t * 262144 + srow * 4096 + n0 * 4 + soff * 2;
        *reinterpret_cast<float4*>(oa)      = f0;
        *reinterpret_cast<float4*>(oa + 16) = f1;
        *reinterpret_cast<float4*>(oa + 32) = f2;
        *reinterpret_cast<float4*>(oa + 48) = f3;
      }
    }
    if (!wlast) {
      asm volatile("s_waitcnt vmcnt(0)" ::: "memory");  // h-frag stores at coherence point
      scan_barrier(flags, g, (unsigned)(t + 2), tid);
    }
  }
}

extern "C" void kernel_launch(void* const* d_in, const int* in_sizes, int n_in,
                              void* d_out, int out_size, void* d_ws, size_t ws_size,
                              hipStream_t stream) {
  const float* x     = (const float*)d_in[0];
  const float* state = (const float*)d_in[1];
  const float* Wih0  = (const float*)d_in[2];
  const float* Whh0  = (const float*)d_in[3];
  const float* b0    = (const float*)d_in[4];
  const float* Wih1  = (const float*)d_in[5];
  const float* Whh1  = (const float*)d_in[6];
  const float* b1    = (const float*)d_in[7];
  float* out = (float*)d_out;

  char* ws = (char*)d_ws;
  unsigned* flags = (unsigned*)(ws + 0);               //   4 KiB (2 sets)
  char*  hbuf     = ws + 4096;                         // 256 KiB ping-pong h (fragment layout)
  f16_t* Wih0h    = (f16_t*)(ws + 266240);
  f16_t* Whh0h    = (f16_t*)(ws + 1314816);
  f16_t* Wih1h    = (f16_t*)(ws + 3411968);
  f16_t* Whh1h    = (f16_t*)(ws + 5509120);
  f16_t* xh       = (f16_t*)(ws + 7606272);            //  32 MiB x f16
  f16_t* out0     = (f16_t*)(ws + 41160704);           //  64 MiB layer0 outputs f16
  float* xp       = (float*)(ws + 108269568);          // 128 MiB input projections f32

  hipMemsetAsync(ws, 0, 4096, stream);
  cvt_kernel<<<8192, 256, 0, stream>>>(x,    xh,    16777216 / 8);
  cvt_kernel<<<256,  256, 0, stream>>>(Wih0, Wih0h,   524288 / 8);
  cvt_kernel<<<512,  256, 0, stream>>>(Whh0, Whh0h,  1048576 / 8);
  cvt_kernel<<<512,  256, 0, stream>>>(Wih1, Wih1h,  1048576 / 8);
  cvt_kernel<<<512,  256, 0, stream>>>(Whh1, Whh1h,  1048576 / 8);

  // layer 0 input projection: [32768,512] @ [1024,512]^T
  gemm_bt_bias<<<dim3((MROWS / TM) * (H_DIM / TN)), 256, 0, stream>>>(
      xh, Wih0h, b0, xp, MROWS, H_DIM, C_DIM);

  (void)hipFuncSetAttribute((const void*)rnn_scan,
                            hipFuncAttributeMaxDynamicSharedMemorySize, 139264);
  float* state_out = out + (size_t)L_DIM * B_DIM * H_DIM;  // 33554432
  rnn_scan<<<16, 256, 139264, stream>>>(xp, Whh0h, state, hbuf, flags,
                                        out0, nullptr, state_out);
  // layer 1 input projection: [32768,1024] @ [1024,1024]^T
  gemm_bt_bias<<<dim3((MROWS / TM) * (H_DIM / TN)), 256, 0, stream>>>(
      out0, Wih1h, b1, xp, MROWS, H_DIM, H_DIM);
  rnn_scan<<<16, 256, 139264, stream>>>(xp, Whh1h, state + B_DIM * H_DIM, hbuf, flags + 512,
                                        nullptr, out, state_out + B_DIM * H_DIM);
}

// Round 6
// 6835.652 us; speedup vs baseline: 3.0988x; 1.0070x over previous
//
#include <hip/hip_runtime.h>
#include <hip/hip_bf16.h>

typedef _Float16 f16_t;
using f16x8  = __attribute__((ext_vector_type(8))) _Float16;
using f32x4  = __attribute__((ext_vector_type(4))) float;
using f32x16 = __attribute__((ext_vector_type(16))) float;
using u64    = unsigned long long;
using u64x2  = __attribute__((ext_vector_type(2))) unsigned long long;

#define L_DIM 512
#define B_DIM 64
#define C_DIM 512
#define H_DIM 1024
#define MROWS (L_DIM * B_DIM) /* 32768 */

// ---------------- f32 -> f16 convert ----------------
__global__ void cvt_kernel(const float* __restrict__ src, f16_t* __restrict__ dst, int n8) {
  int i = blockIdx.x * blockDim.x + threadIdx.x;
  if (i >= n8) return;
  const float4* s4 = reinterpret_cast<const float4*>(src) + (size_t)i * 2;
  float4 a = s4[0], b = s4[1];
  f16x8 o;
  o[0] = (f16_t)a.x; o[1] = (f16_t)a.y; o[2] = (f16_t)a.z; o[3] = (f16_t)a.w;
  o[4] = (f16_t)b.x; o[5] = (f16_t)b.y; o[6] = (f16_t)b.z; o[7] = (f16_t)b.w;
  reinterpret_cast<f16x8*>(dst)[i] = o;
}

// ---------------- async global->LDS 16B ----------------
__device__ inline void gload_lds16(const void* g, void* l) {
  __builtin_amdgcn_global_load_lds(
      (const __attribute__((address_space(1))) unsigned int*)g,
      (__attribute__((address_space(3))) unsigned int*)l, 16, 0, 0);
}

// ---------------- bt-GEMM: C[M,N] = A[M,K] @ B[N,K]^T + bias ----------------
#define TM 128
#define TN 128
#define BKK 64
__global__ __launch_bounds__(256) void gemm_bt_bias(
    const f16_t* __restrict__ A, const f16_t* __restrict__ B,
    const float* __restrict__ bias, float* __restrict__ C,
    int M, int N, int K) {
  __shared__ f16_t As[TM * BKK];
  __shared__ f16_t Bs[TN * BKK];
  const int tid = threadIdx.x;
  const int w = tid >> 6, l = tid & 63;
  const int nbn = N / TN;
  const int bm = blockIdx.x / nbn, bn = blockIdx.x % nbn;
  const int m0 = bm * TM, n0 = bn * TN;
  const int wr = w >> 1, wc = w & 1;
  const int lr = l & 15;
  const int lk = (l >> 4) * 8;
  f32x4 acc[4][4] = {};

  for (int kt = 0; kt < K; kt += BKK) {
#pragma unroll
    for (int r = 0; r < 4; ++r) {
      int p8 = r * 256 + tid;
      int row = p8 >> 3, col = (p8 & 7) * 8;
      gload_lds16(A + (size_t)(m0 + row) * K + kt + col, &As[(size_t)(r * 256 + w * 64) * 8]);
    }
#pragma unroll
    for (int r = 0; r < 4; ++r) {
      int p8 = r * 256 + tid;
      int row = p8 >> 3, col = (p8 & 7) * 8;
      gload_lds16(B + (size_t)(n0 + row) * K + kt + col, &Bs[(size_t)(r * 256 + w * 64) * 8]);
    }
    __syncthreads();
#pragma unroll
    for (int kk = 0; kk < 2; ++kk) {
      f16x8 af[4], bfr[4];
#pragma unroll
      for (int i = 0; i < 4; ++i)
        af[i] = *reinterpret_cast<const f16x8*>(&As[(wr * 64 + i * 16 + lr) * BKK + kk * 32 + lk]);
#pragma unroll
      for (int j = 0; j < 4; ++j)
        bfr[j] = *reinterpret_cast<const f16x8*>(&Bs[(wc * 64 + j * 16 + lr) * BKK + kk * 32 + lk]);
#pragma unroll
      for (int i = 0; i < 4; ++i)
#pragma unroll
        for (int j = 0; j < 4; ++j)
          acc[i][j] = __builtin_amdgcn_mfma_f32_16x16x32_f16(af[i], bfr[j], acc[i][j], 0, 0, 0);
    }
    __syncthreads();
  }
  const int crow = (l >> 4) * 4, ccol = l & 15;
#pragma unroll
  for (int j = 0; j < 4; ++j) {
    int col = n0 + wc * 64 + j * 16 + ccol;
    float bv = bias[col];
#pragma unroll
    for (int i = 0; i < 4; ++i) {
      int rowb = m0 + wr * 64 + i * 16 + crow;
#pragma unroll
      for (int r = 0; r < 4; ++r)
        C[(size_t)(rowb + r) * N + col] = acc[i][j][r] + bv;
    }
  }
}

// 16B coherent load/store (sc0 sc1: L1/L2-bypassing, served at coherence point)
#define GLOAD16(dst, addr) \
  asm volatile("global_load_dwordx4 %0, %1, off sc0 sc1" : "=&v"(dst) : "v"(addr) : "memory")
#define GSTORE16(addr, val) \
  asm volatile("global_store_dwordx4 %0, %1, off sc0 sc1" :: "v"(addr), "v"(val) : "memory")
#define WAITV(n) do { asm volatile("s_waitcnt vmcnt(" #n ")" ::: "memory"); \
                      __builtin_amdgcn_sched_barrier(0); } while (0)

// LDS map (dynamic): [0,128K) W swizzled; [128K,144K) K-reduce; [144K,152K) pk pack
#define RED_OFF 131072
#define PK_OFF  147456
#define SMEM_SZ 155648

// ---------------- recurrent scan: h = tanh(xp_t + h @ W^T) ----------------
// 16 blocks x 256 threads. Block g owns output cols [g*64, g*64+64).
// h ping-pong in MFMA-A-FRAGMENT layout (validated r5):
//   hbuf[t&1][kb][rh][lane][16B]; fragment(kb,rh,lane) =
//   h[row rh*32+(lane&31)][cols kb*16+(lane>>5)*8 ..+8]
// NEW vs r5: waves = (row-half wr, K-half kh) -> disjoint loads (128KB/CU not
// 256KB); each wave does BOTH col-tiles over its K-half; cross-kh LDS reduce;
// pre-barrier wait = vmcnt(NOUT) so HBM out-store acks stay off critical path.
template <int NOUT>
__global__ __launch_bounds__(256, 1) void rnn_scan(
    const float* __restrict__ xp,     // [512][64][1024] f32
    const f16_t* __restrict__ Wr,     // [1024][1024] f16 (W_hh)
    const float* __restrict__ h0in,   // [64][1024] f32 initial state
    char* __restrict__ hbuf,          // 2 x 128KB fragment-layout ping-pong
    unsigned* __restrict__ flags,     // 16 flags (one line)
    f16_t* __restrict__ out_h,        // [512][64][1024] f16 (NOUT==2)
    float* __restrict__ out_f,        // [512][64][1024] f32 (NOUT==4)
    float* __restrict__ state_out) {  // [64][1024] f32 final h
  extern __shared__ char smem[];
  char* pkc = smem + PK_OFF;          // 64 rows x 128B, granule-swizzled
  const int tid = threadIdx.x, g = blockIdx.x;
  const int w = tid >> 6, l = tid & 63;
  const int n0 = g * 64;
  const int wr = w >> 1;              // row half (A rows wr*32..+32)
  const int kh = w & 1;               // K half   (kb wr... kh*32..+32)
  const int la = l & 31, lb = l >> 5;

  // stage W slice (rows n0..n0+63, all K) into LDS with XOR swizzle on 16B granules
  for (int i = 0; i < 32; ++i) {
    int g8 = i * 256 + tid;
    int row = g8 >> 7, cb = g8 & 127;
    f16x8 v = *reinterpret_cast<const f16x8*>(Wr + (size_t)(n0 + row) * H_DIM + cb * 8);
    *reinterpret_cast<f16x8*>(smem + row * 2048 + ((cb ^ (row & 31)) << 4)) = v;
  }
  // init ping fragments (this block's 4 kb chunks) from f32 state
#pragma unroll
  for (int i = 0; i < 2; ++i) {
    int f = tid * 2 + i;                    // [0,512)
    int kbl = f >> 7, rem = f & 127, rh = rem >> 6, lf = rem & 63;
    int row = rh * 32 + (lf & 31);
    int cgl = (4 * g + kbl) * 16 + (lf >> 5) * 8;
    const float* s = h0in + row * H_DIM + cgl;
    float4 a = *reinterpret_cast<const float4*>(s);
    float4 b = *reinterpret_cast<const float4*>(s + 4);
    f16x8 v;
    v[0] = (f16_t)a.x; v[1] = (f16_t)a.y; v[2] = (f16_t)a.z; v[3] = (f16_t)a.w;
    v[4] = (f16_t)b.x; v[5] = (f16_t)b.y; v[6] = (f16_t)b.z; v[7] = (f16_t)b.w;
    GSTORE16(hbuf + g * 8192 + f * 16, v);
  }
  asm volatile("s_waitcnt vmcnt(0)" ::: "memory");
  __syncthreads();
  if (tid < 64) {
    if (tid == 0)
      __hip_atomic_store(&flags[g], 1u, __ATOMIC_RELAXED, __HIP_MEMORY_SCOPE_AGENT);
    int src = tid & 15;
    while (true) {
      unsigned v = __hip_atomic_load(&flags[src], __ATOMIC_RELAXED, __HIP_MEMORY_SCOPE_AGENT);
      if (__all((int)(v >= 1u))) break;
    }
  }
  __syncthreads();

  const char* smem_w0 = smem + la * 2048;            // B rows for tile0 (col la)
  const char* smem_w1 = smem + (32 + la) * 2048;     // B rows for tile1 (col 32+la)
  const int rx = la;                                 // swizzle key (same both tiles)
  const int colg = n0 + kh * 32 + la;                // the col this lane finalizes
  const int pcg = (kh * 32 + la) >> 3;
  const int pco = ((kh * 32 + la) & 7) * 2;

#define MFMA_HALF(bufarr, base)                                                \
  _Pragma("unroll")                                                            \
  for (int i_ = 0; i_ < 16; ++i_) {                                            \
    int cb_ = ((((base) + i_) * 2 + lb) ^ rx) << 4;                            \
    f16x8 a_ = __builtin_bit_cast(f16x8, bufarr[i_]);                          \
    f16x8 b0_ = *reinterpret_cast<const f16x8*>(smem_w0 + cb_);                \
    f16x8 b1_ = *reinterpret_cast<const f16x8*>(smem_w1 + cb_);                \
    acc0 = __builtin_amdgcn_mfma_f32_32x32x16_f16(a_, b0_, acc0, 0, 0, 0);     \
    acc1 = __builtin_amdgcn_mfma_f32_32x32x16_f16(a_, b1_, acc1, 0, 0, 0);     \
  }

  for (int t = 0; t < 512; ++t) {
    const char* hs = hbuf + (size_t)(t & 1) * 131072;
    char* hd = hbuf + (size_t)((t + 1) & 1) * 131072;
    const char* hb = hs + wr * 1024 + l * 16;

    // this wave's DISJOINT 32KB of h: kb in [kh*32, kh*32+32), rows wr-half
    u64x2 bf0[16], bf1[16];
#pragma unroll
    for (int i = 0; i < 16; ++i) GLOAD16(bf0[i], hb + (kh * 32 + i) * 2048);
#pragma unroll
    for (int i = 0; i < 16; ++i) GLOAD16(bf1[i], hb + (kh * 32 + 16 + i) * 2048);
    // xp for the tile this wave finalizes (tile kh)
    float xv[16];
#pragma unroll
    for (int r = 0; r < 16; ++r) {
      int row = wr * 32 + (r & 3) + 8 * (r >> 2) + 4 * lb;
      xv[r] = xp[(size_t)t * (B_DIM * H_DIM) + row * H_DIM + colg];
    }

    f32x16 acc0 = {}, acc1 = {};
    WAITV(32);                 // leftover out-acks + chunk0 done
    MFMA_HALF(bf0, kh * 32);
    WAITV(16);                 // chunk1 done
    MFMA_HALF(bf1, kh * 32 + 16);
    WAITV(0);                  // xp done

    // cross-kh reduction: give away the OTHER tile's partial, keep mine
    {
      f32x16 oth = kh ? acc0 : acc1;
      char* rw = smem + RED_OFF + (size_t)(wr * 2 + (kh ^ 1)) * 4096;
#pragma unroll
      for (int i4 = 0; i4 < 4; ++i4) {
        f32x4 q = {oth[i4 * 4], oth[i4 * 4 + 1], oth[i4 * 4 + 2], oth[i4 * 4 + 3]};
        *reinterpret_cast<f32x4*>(rw + i4 * 1024 + l * 16) = q;
      }
    }
    __syncthreads();
    f32x16 mine = kh ? acc1 : acc0;
    {
      const char* rr = smem + RED_OFF + (size_t)(wr * 2 + kh) * 4096;
#pragma unroll
      for (int i4 = 0; i4 < 4; ++i4) {
        f32x4 q = *reinterpret_cast<const f32x4*>(rr + i4 * 1024 + l * 16);
        mine[i4 * 4] += q[0]; mine[i4 * 4 + 1] += q[1];
        mine[i4 * 4 + 2] += q[2]; mine[i4 * 4 + 3] += q[3];
      }
    }

    const bool wlast = (t == 511);
#pragma unroll
    for (int r = 0; r < 16; ++r) {
      int row = wr * 32 + (r & 3) + 8 * (r >> 2) + 4 * lb;
      float z = mine[r] + xv[r];
      z = fminf(fmaxf(z, -15.f), 15.f);
      float e = __expf(2.f * z);
      float h = 1.f - __fdividef(2.f, e + 1.f);
      f16_t hf = (f16_t)h;
      *reinterpret_cast<unsigned short*>(
          pkc + row * 128 + ((pcg ^ (row & 7)) << 4) + pco) =
          __builtin_bit_cast(unsigned short, hf);
      if (wlast) state_out[row * H_DIM + colg] = (float)hf;
    }
    __syncthreads();  // pack visible block-wide

    // h-frag stores FIRST (gate the flag), then sequence-out stores (don't)
#pragma unroll
    for (int i = 0; i < 2; ++i) {
      int f = tid * 2 + i;
      int kbl = f >> 7, rem = f & 127, rh = rem >> 6, lf = rem & 63;
      int row = rh * 32 + (lf & 31);
      int cg = kbl * 2 + (lf >> 5);
      u64x2 q = *reinterpret_cast<const u64x2*>(pkc + row * 128 + ((cg ^ (row & 7)) << 4));
      GSTORE16(hd + g * 8192 + f * 16, q);
    }
    {
      const int srow = tid >> 2;
      const int cg0 = (tid & 3) * 2;
      u64x2 q0 = *reinterpret_cast<const u64x2*>(pkc + srow * 128 + ((cg0 ^ (srow & 7)) << 4));
      u64x2 q1 = *reinterpret_cast<const u64x2*>(pkc + srow * 128 + (((cg0 + 1) ^ (srow & 7)) << 4));
      const int soff = (tid & 3) * 32;
      if constexpr (NOUT == 2) {
        char* oa = (char*)out_h + (size_t)t * 131072 + srow * 2048 + n0 * 2 + soff;
        *reinterpret_cast<u64x2*>(oa) = q0;
        *reinterpret_cast<u64x2*>(oa + 16) = q1;
      } else {
        f16x8 a0 = __builtin_bit_cast(f16x8, q0);
        f16x8 a1 = __builtin_bit_cast(f16x8, q1);
        float4 f0 = {(float)a0[0], (float)a0[1], (float)a0[2], (float)a0[3]};
        float4 f1 = {(float)a0[4], (float)a0[5], (float)a0[6], (float)a0[7]};
        float4 f2 = {(float)a1[0], (float)a1[1], (float)a1[2], (float)a1[3]};
        float4 f3 = {(float)a1[4], (float)a1[5], (float)a1[6], (float)a1[7]};
        char* oa = (char*)out_f + (size_t)t * 262144 + srow * 4096 + n0 * 4 + soff * 2;
        *reinterpret_cast<float4*>(oa)      = f0;
        *reinterpret_cast<float4*>(oa + 16) = f1;
        *reinterpret_cast<float4*>(oa + 32) = f2;
        *reinterpret_cast<float4*>(oa + 48) = f3;
      }
    }
    if (!wlast) {
      // wait ONLY for the 2 h-frag stores (oldest); NOUT out-stores may fly
      if constexpr (NOUT == 2)
        asm volatile("s_waitcnt vmcnt(2) lgkmcnt(0)" ::: "memory");
      else
        asm volatile("s_waitcnt vmcnt(4) lgkmcnt(0)" ::: "memory");
      __builtin_amdgcn_sched_barrier(0);
      __builtin_amdgcn_s_barrier();
      unsigned target = (unsigned)(t + 2);
      if (tid < 64) {
        if (tid == 0)
          __hip_atomic_store(&flags[g], target, __ATOMIC_RELAXED, __HIP_MEMORY_SCOPE_AGENT);
        int src = tid & 15;
        while (true) {
          unsigned v = __hip_atomic_load(&flags[src], __ATOMIC_RELAXED, __HIP_MEMORY_SCOPE_AGENT);
          if (__all((int)(v >= target))) break;
        }
      }
      __builtin_amdgcn_s_barrier();
    }
  }
#undef MFMA_HALF
}

extern "C" void kernel_launch(void* const* d_in, const int* in_sizes, int n_in,
                              void* d_out, int out_size, void* d_ws, size_t ws_size,
                              hipStream_t stream) {
  const float* x     = (const float*)d_in[0];
  const float* state = (const float*)d_in[1];
  const float* Wih0  = (const float*)d_in[2];
  const float* Whh0  = (const float*)d_in[3];
  const float* b0    = (const float*)d_in[4];
  const float* Wih1  = (const float*)d_in[5];
  const float* Whh1  = (const float*)d_in[6];
  const float* b1    = (const float*)d_in[7];
  float* out = (float*)d_out;

  char* ws = (char*)d_ws;
  unsigned* flags = (unsigned*)(ws + 0);               //   4 KiB (2 sets)
  char*  hbuf     = ws + 4096;                         // 256 KiB ping-pong h (fragment layout)
  f16_t* Wih0h    = (f16_t*)(ws + 266240);
  f16_t* Whh0h    = (f16_t*)(ws + 1314816);
  f16_t* Wih1h    = (f16_t*)(ws + 3411968);
  f16_t* Whh1h    = (f16_t*)(ws + 5509120);
  f16_t* xh       = (f16_t*)(ws + 7606272);            //  32 MiB x f16
  f16_t* out0     = (f16_t*)(ws + 41160704);           //  64 MiB layer0 outputs f16
  float* xp       = (float*)(ws + 108269568);          // 128 MiB input projections f32

  hipMemsetAsync(ws, 0, 4096, stream);
  cvt_kernel<<<8192, 256, 0, stream>>>(x,    xh,    16777216 / 8);
  cvt_kernel<<<256,  256, 0, stream>>>(Wih0, Wih0h,   524288 / 8);
  cvt_kernel<<<512,  256, 0, stream>>>(Whh0, Whh0h,  1048576 / 8);
  cvt_kernel<<<512,  256, 0, stream>>>(Wih1, Wih1h,  1048576 / 8);
  cvt_kernel<<<512,  256, 0, stream>>>(Whh1, Whh1h,  1048576 / 8);

  // layer 0 input projection: [32768,512] @ [1024,512]^T
  gemm_bt_bias<<<dim3((MROWS / TM) * (H_DIM / TN)), 256, 0, stream>>>(
      xh, Wih0h, b0, xp, MROWS, H_DIM, C_DIM);

  (void)hipFuncSetAttribute((const void*)rnn_scan<2>,
                            hipFuncAttributeMaxDynamicSharedMemorySize, SMEM_SZ);
  (void)hipFuncSetAttribute((const void*)rnn_scan<4>,
                            hipFuncAttributeMaxDynamicSharedMemorySize, SMEM_SZ);
  float* state_out = out + (size_t)L_DIM * B_DIM * H_DIM;  // 33554432
  rnn_scan<2><<<16, 256, SMEM_SZ, stream>>>(xp, Whh0h, state, hbuf, flags,
                                            out0, nullptr, state_out);
  // layer 1 input projection: [32768,1024] @ [1024,1024]^T
  gemm_bt_bias<<<dim3((MROWS / TM) * (H_DIM / TN)), 256, 0, stream>>>(
      out0, Wih1h, b1, xp, MROWS, H_DIM, H_DIM);
  rnn_scan<4><<<16, 256, SMEM_SZ, stream>>>(xp, Whh1h, state + B_DIM * H_DIM, hbuf, flags + 512,
                                            nullptr, out, state_out + B_DIM * H_DIM);
}

// Round 9
// 3681.743 us; speedup vs baseline: 5.7534x; 1.8566x over previous
//
#include <hip/hip_runtime.h>
#include <hip/hip_bf16.h>

typedef _Float16 f16_t;
using f16x8  = __attribute__((ext_vector_type(8))) _Float16;
using f32x4  = __attribute__((ext_vector_type(4))) float;
using f32x16 = __attribute__((ext_vector_type(16))) float;
using u64    = unsigned long long;
using u64x2  = __attribute__((ext_vector_type(2))) unsigned long long;

#define L_DIM 512
#define B_DIM 64
#define C_DIM 512
#define H_DIM 1024
#define MROWS (L_DIM * B_DIM) /* 32768 */
#define SLOT_SZ 131072        /* one full h state in fragment layout */

// ---------------- f32 -> f16 convert ----------------
__global__ void cvt_kernel(const float* __restrict__ src, f16_t* __restrict__ dst, int n8) {
  int i = blockIdx.x * blockDim.x + threadIdx.x;
  if (i >= n8) return;
  const float4* s4 = reinterpret_cast<const float4*>(src) + (size_t)i * 2;
  float4 a = s4[0], b = s4[1];
  f16x8 o;
  o[0] = (f16_t)a.x; o[1] = (f16_t)a.y; o[2] = (f16_t)a.z; o[3] = (f16_t)a.w;
  o[4] = (f16_t)b.x; o[5] = (f16_t)b.y; o[6] = (f16_t)b.z; o[7] = (f16_t)b.w;
  reinterpret_cast<f16x8*>(dst)[i] = o;
}

// ---------------- async global->LDS 16B ----------------
__device__ inline void gload_lds16(const void* g, void* l) {
  __builtin_amdgcn_global_load_lds(
      (const __attribute__((address_space(1))) unsigned int*)g,
      (__attribute__((address_space(3))) unsigned int*)l, 16, 0, 0);
}

// ---------------- bt-GEMM: C[M,N] = A[M,K] @ B[N,K]^T + bias, f16 out ----------------
#define TM 128
#define TN 128
#define BKK 64
__global__ __launch_bounds__(256) void gemm_bt_bias(
    const f16_t* __restrict__ A, const f16_t* __restrict__ B,
    const float* __restrict__ bias, f16_t* __restrict__ C,
    int M, int N, int K) {
  __shared__ f16_t As[TM * BKK];
  __shared__ f16_t Bs[TN * BKK];
  const int tid = threadIdx.x;
  const int w = tid >> 6, l = tid & 63;
  const int nbn = N / TN;
  const int bm = blockIdx.x / nbn, bn = blockIdx.x % nbn;
  const int m0 = bm * TM, n0 = bn * TN;
  const int wr = w >> 1, wc = w & 1;
  const int lr = l & 15;
  const int lk = (l >> 4) * 8;
  f32x4 acc[4][4] = {};

  for (int kt = 0; kt < K; kt += BKK) {
#pragma unroll
    for (int r = 0; r < 4; ++r) {
      int p8 = r * 256 + tid;
      int row = p8 >> 3, col = (p8 & 7) * 8;
      gload_lds16(A + (size_t)(m0 + row) * K + kt + col, &As[(size_t)(r * 256 + w * 64) * 8]);
    }
#pragma unroll
    for (int r = 0; r < 4; ++r) {
      int p8 = r * 256 + tid;
      int row = p8 >> 3, col = (p8 & 7) * 8;
      gload_lds16(B + (size_t)(n0 + row) * K + kt + col, &Bs[(size_t)(r * 256 + w * 64) * 8]);
    }
    __syncthreads();
#pragma unroll
    for (int kk = 0; kk < 2; ++kk) {
      f16x8 af[4], bfr[4];
#pragma unroll
      for (int i = 0; i < 4; ++i)
        af[i] = *reinterpret_cast<const f16x8*>(&As[(wr * 64 + i * 16 + lr) * BKK + kk * 32 + lk]);
#pragma unroll
      for (int j = 0; j < 4; ++j)
        bfr[j] = *reinterpret_cast<const f16x8*>(&Bs[(wc * 64 + j * 16 + lr) * BKK + kk * 32 + lk]);
#pragma unroll
      for (int i = 0; i < 4; ++i)
#pragma unroll
        for (int j = 0; j < 4; ++j)
          acc[i][j] = __builtin_amdgcn_mfma_f32_16x16x32_f16(af[i], bfr[j], acc[i][j], 0, 0, 0);
    }
    __syncthreads();
  }
  const int crow = (l >> 4) * 4, ccol = l & 15;
#pragma unroll
  for (int j = 0; j < 4; ++j) {
    int col = n0 + wc * 64 + j * 16 + ccol;
    float bv = bias[col];
#pragma unroll
    for (int i = 0; i < 4; ++i) {
      int rowb = m0 + wr * 64 + i * 16 + crow;
#pragma unroll
      for (int r = 0; r < 4; ++r)
        C[(size_t)(rowb + r) * N + col] = (f16_t)(acc[i][j][r] + bv);
    }
  }
}

// 16B L3-coherent load/store (validated r5/r6 protocol)
#define GLOAD16(dst, addr) \
  asm volatile("global_load_dwordx4 %0, %1, off sc0 sc1" : "=&v"(dst) : "v"(addr) : "memory")
#define GSTORE16(addr, val) \
  asm volatile("global_store_dwordx4 %0, %1, off sc0 sc1" :: "v"(addr), "v"(val) : "memory")
#define WAITV(n) do { asm volatile("s_waitcnt vmcnt(" #n ")" ::: "memory"); \
                      __builtin_amdgcn_sched_barrier(0); } while (0)

// LDS maps. Layer0: [0,128K) W; [128K,144K) RED; [144K,152K) pk(128B rows)
// Layer1: [0,64K) Wih; [64K,128K) Whh; [128K,136K) RED; [136K,140K) pk(64B rows)
#define RED_OFF  131072
#define PK_OFF   147456
#define L1_RED   131072
#define L1_PK    139264
#define SMEM_SZ  155648

// ---------------- fused 2-layer pipelined scan ----------------
// Blocks 0..15: layer0, cols [g*64,+64). h0 published per-step to write-once
//   slots (513 x 128KB). Barrier group: flags0[16]. L0 ALWAYS publishes
//   flags0=t+2 (incl. final t=511 -> 513) so L1 can drain. (r8 deadlock fix)
// Blocks 16..47: layer1, cols [g1*32,+32), one step behind. Consumes h0 slot
//   t+1 (ready when flags0>=t+2) + own h1 ping-pong (flags1[32]).
__global__ __launch_bounds__(256, 1) void fused_scan(
    const f16_t* __restrict__ xpH,    // [512][64][1024] f16 (layer0 input proj)
    const f16_t* __restrict__ Whh0,   // [1024][1024] f16
    const f16_t* __restrict__ Wih1,   // [1024][1024] f16
    const f16_t* __restrict__ Whh1,   // [1024][1024] f16
    const float* __restrict__ b1,     // [1024]
    const float* __restrict__ state_in, // [2][64][1024] f32
    char* __restrict__ h0slots,       // 513 x SLOT_SZ fragment slots
    char* __restrict__ h1buf,         // 2 x SLOT_SZ ping-pong
    unsigned* __restrict__ flags0,    // 16
    unsigned* __restrict__ flags1,    // 32
    float* __restrict__ out,          // [512][64][1024] f32 (layer1 seq)
    float* __restrict__ state_out) {  // [2][64][1024] f32
  extern __shared__ char smem[];
  const int tid = threadIdx.x;
  const int w = tid >> 6, l = tid & 63;
  const int wr = w >> 1, kh = w & 1;
  const int la = l & 31, lb = l >> 5;

  if (blockIdx.x < 16) {
    // ================= LAYER 0 (r6-validated body, slot addressing) =================
    char* pkc = smem + PK_OFF;
    const int g = blockIdx.x;
    const int n0 = g * 64;
    for (int i = 0; i < 32; ++i) {
      int g8 = i * 256 + tid;
      int row = g8 >> 7, cb = g8 & 127;
      f16x8 v = *reinterpret_cast<const f16x8*>(Whh0 + (size_t)(n0 + row) * H_DIM + cb * 8);
      *reinterpret_cast<f16x8*>(smem + row * 2048 + ((cb ^ (row & 31)) << 4)) = v;
    }
#pragma unroll
    for (int i = 0; i < 2; ++i) {
      int f = tid * 2 + i;
      int kbl = f >> 7, rem = f & 127, rh = rem >> 6, lf = rem & 63;
      int row = rh * 32 + (lf & 31);
      int cgl = (4 * g + kbl) * 16 + (lf >> 5) * 8;
      const float* s = state_in + row * H_DIM + cgl;
      float4 a = *reinterpret_cast<const float4*>(s);
      float4 b = *reinterpret_cast<const float4*>(s + 4);
      f16x8 v;
      v[0] = (f16_t)a.x; v[1] = (f16_t)a.y; v[2] = (f16_t)a.z; v[3] = (f16_t)a.w;
      v[4] = (f16_t)b.x; v[5] = (f16_t)b.y; v[6] = (f16_t)b.z; v[7] = (f16_t)b.w;
      GSTORE16(h0slots + g * 8192 + f * 16, v);
    }
    asm volatile("s_waitcnt vmcnt(0)" ::: "memory");
    __syncthreads();
    if (tid < 64) {
      if (tid == 0)
        __hip_atomic_store(&flags0[g], 1u, __ATOMIC_RELAXED, __HIP_MEMORY_SCOPE_AGENT);
      int src = tid & 15;
      unsigned v;
      do { v = __hip_atomic_load(&flags0[src], __ATOMIC_RELAXED, __HIP_MEMORY_SCOPE_AGENT);
      } while (!__all((int)(v >= 1u)));
    }
    __syncthreads();

    const char* smem_w0 = smem + la * 2048;
    const char* smem_w1 = smem + (32 + la) * 2048;
    const int rx = la;
    const int colg = n0 + kh * 32 + la;
    const int pcg = (kh * 32 + la) >> 3;
    const int pco = ((kh * 32 + la) & 7) * 2;

#define MFMA_HALF(bufarr, base)                                                \
  _Pragma("unroll")                                                            \
  for (int i_ = 0; i_ < 16; ++i_) {                                            \
    int cb_ = ((((base) + i_) * 2 + lb) ^ rx) << 4;                            \
    f16x8 a_ = __builtin_bit_cast(f16x8, bufarr[i_]);                          \
    f16x8 b0_ = *reinterpret_cast<const f16x8*>(smem_w0 + cb_);                \
    f16x8 b1_ = *reinterpret_cast<const f16x8*>(smem_w1 + cb_);                \
    acc0 = __builtin_amdgcn_mfma_f32_32x32x16_f16(a_, b0_, acc0, 0, 0, 0);     \
    acc1 = __builtin_amdgcn_mfma_f32_32x32x16_f16(a_, b1_, acc1, 0, 0, 0);     \
  }

    for (int t = 0; t < 512; ++t) {
      const char* hb = h0slots + (size_t)t * SLOT_SZ + wr * 1024 + l * 16;
      char* hd = h0slots + (size_t)(t + 1) * SLOT_SZ + g * 8192;
      u64x2 bf0[16], bf1[16];
#pragma unroll
      for (int i = 0; i < 16; ++i) GLOAD16(bf0[i], hb + (kh * 32 + i) * 2048);
#pragma unroll
      for (int i = 0; i < 16; ++i) GLOAD16(bf1[i], hb + (kh * 32 + 16 + i) * 2048);
      float xv[16];
#pragma unroll
      for (int r = 0; r < 16; ++r) {
        int row = wr * 32 + (r & 3) + 8 * (r >> 2) + 4 * lb;
        xv[r] = (float)xpH[(size_t)t * 65536 + row * H_DIM + colg];
      }
      f32x16 acc0 = {}, acc1 = {};
      WAITV(32);
      MFMA_HALF(bf0, kh * 32);
      WAITV(16);
      MFMA_HALF(bf1, kh * 32 + 16);
      WAITV(0);
      {
        f32x16 oth = kh ? acc0 : acc1;
        char* rw = smem + RED_OFF + (size_t)(wr * 2 + (kh ^ 1)) * 4096;
#pragma unroll
        for (int i4 = 0; i4 < 4; ++i4) {
          f32x4 q = {oth[i4 * 4], oth[i4 * 4 + 1], oth[i4 * 4 + 2], oth[i4 * 4 + 3]};
          *reinterpret_cast<f32x4*>(rw + i4 * 1024 + l * 16) = q;
        }
      }
      __syncthreads();
      f32x16 mine = kh ? acc1 : acc0;
      {
        const char* rr = smem + RED_OFF + (size_t)(wr * 2 + kh) * 4096;
#pragma unroll
        for (int i4 = 0; i4 < 4; ++i4) {
          f32x4 q = *reinterpret_cast<const f32x4*>(rr + i4 * 1024 + l * 16);
          mine[i4 * 4] += q[0]; mine[i4 * 4 + 1] += q[1];
          mine[i4 * 4 + 2] += q[2]; mine[i4 * 4 + 3] += q[3];
        }
      }
      const bool wlast = (t == 511);
#pragma unroll
      for (int r = 0; r < 16; ++r) {
        int row = wr * 32 + (r & 3) + 8 * (r >> 2) + 4 * lb;
        float z = mine[r] + xv[r];
        z = fminf(fmaxf(z, -15.f), 15.f);
        float e = __expf(2.f * z);
        float h = 1.f - __fdividef(2.f, e + 1.f);
        f16_t hf = (f16_t)h;
        *reinterpret_cast<unsigned short*>(
            pkc + row * 128 + ((pcg ^ (row & 7)) << 4) + pco) =
            __builtin_bit_cast(unsigned short, hf);
        if (wlast) state_out[row * H_DIM + colg] = (float)hf;
      }
      __syncthreads();
#pragma unroll
      for (int i = 0; i < 2; ++i) {
        int f = tid * 2 + i;
        int kbl = f >> 7, rem = f & 127, rh = rem >> 6, lf = rem & 63;
        int row = rh * 32 + (lf & 31);
        int cg = kbl * 2 + (lf >> 5);
        u64x2 q = *reinterpret_cast<const u64x2*>(pkc + row * 128 + ((cg ^ (row & 7)) << 4));
        GSTORE16(hd + f * 16, q);
      }
      asm volatile("s_waitcnt vmcnt(0) lgkmcnt(0)" ::: "memory");
      __builtin_amdgcn_sched_barrier(0);
      // ALWAYS publish (deadlock fix): L1 waits for flags0 = t+2 up to 513.
      __builtin_amdgcn_s_barrier();
      unsigned target = (unsigned)(t + 2);
      if (tid == 0)
        __hip_atomic_store(&flags0[g], target, __ATOMIC_RELAXED, __HIP_MEMORY_SCOPE_AGENT);
      if (!wlast) {
        if (tid < 64) {
          int src = tid & 15;
          unsigned v;
          do { v = __hip_atomic_load(&flags0[src], __ATOMIC_RELAXED, __HIP_MEMORY_SCOPE_AGENT);
          } while (!__all((int)(v >= target)));
        }
        __builtin_amdgcn_s_barrier();
      }
    }
#undef MFMA_HALF
  } else {
    // ================= LAYER 1 =================
    char* pk1 = smem + L1_PK;
    const int g1 = blockIdx.x - 16;
    const int n1 = g1 * 32;
    for (int i = 0; i < 16; ++i) {
      int g8 = i * 256 + tid;
      int row = g8 >> 7, cb = g8 & 127;
      f16x8 v = *reinterpret_cast<const f16x8*>(Wih1 + (size_t)(n1 + row) * H_DIM + cb * 8);
      *reinterpret_cast<f16x8*>(smem + row * 2048 + ((cb ^ row) << 4)) = v;
    }
    for (int i = 0; i < 16; ++i) {
      int g8 = i * 256 + tid;
      int row = g8 >> 7, cb = g8 & 127;
      f16x8 v = *reinterpret_cast<const f16x8*>(Whh1 + (size_t)(n1 + row) * H_DIM + cb * 8);
      *reinterpret_cast<f16x8*>(smem + 65536 + row * 2048 + ((cb ^ row) << 4)) = v;
    }
    {
      int kbl = tid >> 7, rem = tid & 127, rh = rem >> 6, lf = rem & 63;
      int row = rh * 32 + (lf & 31);
      int cgl = (2 * g1 + kbl) * 16 + (lf >> 5) * 8;
      const float* s = state_in + 65536 + row * H_DIM + cgl;
      float4 a = *reinterpret_cast<const float4*>(s);
      float4 b = *reinterpret_cast<const float4*>(s + 4);
      f16x8 v;
      v[0] = (f16_t)a.x; v[1] = (f16_t)a.y; v[2] = (f16_t)a.z; v[3] = (f16_t)a.w;
      v[4] = (f16_t)b.x; v[5] = (f16_t)b.y; v[6] = (f16_t)b.z; v[7] = (f16_t)b.w;
      GSTORE16(h1buf + (2 * g1 + kbl) * 2048 + rh * 1024 + lf * 16, v);
    }
    asm volatile("s_waitcnt vmcnt(0)" ::: "memory");
    __syncthreads();
    if (tid < 64) {
      if (tid == 0)
        __hip_atomic_store(&flags1[g1], 1u, __ATOMIC_RELAXED, __HIP_MEMORY_SCOPE_AGENT);
      const unsigned* src = (tid < 16) ? &flags0[tid] : &flags1[(tid - 16) & 31];
      unsigned tgt = (tid < 16) ? 2u : 1u;
      unsigned v;
      do { v = __hip_atomic_load(src, __ATOMIC_RELAXED, __HIP_MEMORY_SCOPE_AGENT);
      } while (!__all((int)(v >= tgt)));
    }
    __syncthreads();

    const char* wih_base = smem + la * 2048;
    const char* whh_base = smem + 65536 + la * 2048;
    const int rx = la;
    const float bv1 = b1[n1 + la];
    const int pcg1 = la >> 3, pco1 = (la & 7) * 2;

#define MFMA16_L1(bufarr, wbase, kbase)                                        \
  _Pragma("unroll")                                                            \
  for (int i_ = 0; i_ < 16; ++i_) {                                            \
    int cb_ = ((((kbase) + i_) * 2 + lb) ^ rx) << 4;                           \
    f16x8 a_ = __builtin_bit_cast(f16x8, bufarr[i_]);                          \
    f16x8 b_ = *reinterpret_cast<const f16x8*>((wbase) + cb_);                 \
    if (i_ & 1) accB = __builtin_amdgcn_mfma_f32_32x32x16_f16(a_, b_, accB, 0, 0, 0); \
    else        accA = __builtin_amdgcn_mfma_f32_32x32x16_f16(a_, b_, accA, 0, 0, 0); \
  }

    for (int t = 0; t < 512; ++t) {
      const char* hb0 = h0slots + (size_t)(t + 1) * SLOT_SZ + wr * 1024 + l * 16;
      const char* hb1 = h1buf + (size_t)(t & 1) * SLOT_SZ + wr * 1024 + l * 16;
      char* h1d = h1buf + (size_t)((t + 1) & 1) * SLOT_SZ;
      u64x2 bf0[16], bf1[16];
#pragma unroll
      for (int i = 0; i < 16; ++i) GLOAD16(bf0[i], hb0 + (kh * 32 + i) * 2048);
#pragma unroll
      for (int i = 0; i < 16; ++i) GLOAD16(bf1[i], hb0 + (kh * 32 + 16 + i) * 2048);
      f32x16 accA = {}, accB = {};
      WAITV(16);                     // prev outs (<=2) + c0
      MFMA16_L1(bf0, wih_base, kh * 32);
#pragma unroll
      for (int i = 0; i < 16; ++i) GLOAD16(bf0[i], hb1 + (kh * 32 + i) * 2048);
      WAITV(16);                     // c1
      MFMA16_L1(bf1, wih_base, kh * 32 + 16);
#pragma unroll
      for (int i = 0; i < 16; ++i) GLOAD16(bf1[i], hb1 + (kh * 32 + 16 + i) * 2048);
      WAITV(16);                     // c2
      MFMA16_L1(bf0, whh_base, kh * 32);
      WAITV(0);                      // c3
      MFMA16_L1(bf1, whh_base, kh * 32 + 16);

      if (kh) {
        char* rw = smem + L1_RED + wr * 4096;
#pragma unroll
        for (int i4 = 0; i4 < 4; ++i4) {
          f32x4 q = {accA[i4 * 4] + accB[i4 * 4],
                     accA[i4 * 4 + 1] + accB[i4 * 4 + 1],
                     accA[i4 * 4 + 2] + accB[i4 * 4 + 2],
                     accA[i4 * 4 + 3] + accB[i4 * 4 + 3]};
          *reinterpret_cast<f32x4*>(rw + i4 * 1024 + l * 16) = q;
        }
      }
      __syncthreads();
      const bool wlast = (t == 511);
      if (!kh) {
        const char* rr = smem + L1_RED + wr * 4096;
        float rd[16];
#pragma unroll
        for (int i4 = 0; i4 < 4; ++i4) {
          f32x4 q = *reinterpret_cast<const f32x4*>(rr + i4 * 1024 + l * 16);
          rd[i4 * 4] = q[0]; rd[i4 * 4 + 1] = q[1];
          rd[i4 * 4 + 2] = q[2]; rd[i4 * 4 + 3] = q[3];
        }
#pragma unroll
        for (int r = 0; r < 16; ++r) {
          int row = wr * 32 + (r & 3) + 8 * (r >> 2) + 4 * lb;
          float z = accA[r] + accB[r] + rd[r] + bv1;
          z = fminf(fmaxf(z, -15.f), 15.f);
          float e = __expf(2.f * z);
          float h = 1.f - __fdividef(2.f, e + 1.f);
          f16_t hf = (f16_t)h;
          *reinterpret_cast<unsigned short*>(
              pk1 + row * 64 + ((pcg1 ^ (row & 3)) << 4) + pco1) =
              __builtin_bit_cast(unsigned short, hf);
          if (wlast) state_out[65536 + row * H_DIM + n1 + la] = (float)hf;
        }
      }
      __syncthreads();
      {
        int kbl = tid >> 7, rem = tid & 127, rh = rem >> 6, lf = rem & 63;
        int row = rh * 32 + (lf & 31);
        int cg = kbl * 2 + (lf >> 5);
        u64x2 q = *reinterpret_cast<const u64x2*>(pk1 + row * 64 + ((cg ^ (row & 3)) << 4));
        GSTORE16(h1d + (2 * g1 + kbl) * 2048 + rh * 1024 + lf * 16, q);
      }
      {
        int srow = tid >> 2, cg0 = tid & 3;
        u64x2 q = *reinterpret_cast<const u64x2*>(pk1 + srow * 64 + ((cg0 ^ (srow & 3)) << 4));
        f16x8 a0 = __builtin_bit_cast(f16x8, q);
        float4 f0 = {(float)a0[0], (float)a0[1], (float)a0[2], (float)a0[3]};
        float4 f1 = {(float)a0[4], (float)a0[5], (float)a0[6], (float)a0[7]};
        char* oa = (char*)out + (size_t)t * 262144 + srow * 4096 + (n1 + cg0 * 8) * 4;
        *reinterpret_cast<float4*>(oa) = f0;
        *reinterpret_cast<float4*>(oa + 16) = f1;
      }
      asm volatile("s_waitcnt vmcnt(2) lgkmcnt(0)" ::: "memory");
      __builtin_amdgcn_sched_barrier(0);
      if (!wlast) {
        __builtin_amdgcn_s_barrier();
        unsigned t1t = (unsigned)(t + 2), t0t = (unsigned)(t + 3);
        if (tid < 64) {
          if (tid == 0)
            __hip_atomic_store(&flags1[g1], t1t, __ATOMIC_RELAXED, __HIP_MEMORY_SCOPE_AGENT);
          const unsigned* src = (tid < 16) ? &flags0[tid] : &flags1[(tid - 16) & 31];
          unsigned tgt = (tid < 16) ? t0t : t1t;
          unsigned v;
          do { v = __hip_atomic_load(src, __ATOMIC_RELAXED, __HIP_MEMORY_SCOPE_AGENT);
          } while (!__all((int)(v >= tgt)));
        }
        __builtin_amdgcn_s_barrier();
      }
    }
#undef MFMA16_L1
  }
}

extern "C" void kernel_launch(void* const* d_in, const int* in_sizes, int n_in,
                              void* d_out, int out_size, void* d_ws, size_t ws_size,
                              hipStream_t stream) {
  const float* x     = (const float*)d_in[0];
  const float* state = (const float*)d_in[1];
  const float* Wih0  = (const float*)d_in[2];
  const float* Whh0  = (const float*)d_in[3];
  const float* b0    = (const float*)d_in[4];
  const float* Wih1  = (const float*)d_in[5];
  const float* Whh1  = (const float*)d_in[6];
  const float* b1    = (const float*)d_in[7];
  float* out = (float*)d_out;

  char* ws = (char*)d_ws;
  unsigned* flags0 = (unsigned*)(ws + 0);              // 16
  unsigned* flags1 = (unsigned*)(ws + 1024);           // 32
  char*  h1buf    = ws + 4096;                         // 256 KiB
  char*  h0slots  = ws + 266240;                       // 513 x 128 KiB = 64.1 MiB
  f16_t* Whh0h    = (f16_t*)(ws + 67506176);           // 2 MiB
  f16_t* Wih1h    = (f16_t*)(ws + 69603328);           // 2 MiB
  f16_t* Whh1h    = (f16_t*)(ws + 71700480);           // 2 MiB
  f16_t* Wih0h    = (f16_t*)(ws + 73797632);           // 1 MiB
  f16_t* xh       = (f16_t*)(ws + 74846208);           // 32 MiB
  f16_t* xpH      = (f16_t*)(ws + 108400640);          // 64 MiB f16 xp

  hipMemsetAsync(ws, 0, 4096, stream);
  cvt_kernel<<<8192, 256, 0, stream>>>(x,    xh,    16777216 / 8);
  cvt_kernel<<<256,  256, 0, stream>>>(Wih0, Wih0h,   524288 / 8);
  cvt_kernel<<<512,  256, 0, stream>>>(Whh0, Whh0h,  1048576 / 8);
  cvt_kernel<<<512,  256, 0, stream>>>(Wih1, Wih1h,  1048576 / 8);
  cvt_kernel<<<512,  256, 0, stream>>>(Whh1, Whh1h,  1048576 / 8);

  // layer 0 input projection: [32768,512] @ [1024,512]^T -> f16 xp
  gemm_bt_bias<<<dim3((MROWS / TM) * (H_DIM / TN)), 256, 0, stream>>>(
      xh, Wih0h, b0, xpH, MROWS, H_DIM, C_DIM);

  (void)hipFuncSetAttribute((const void*)fused_scan,
                            hipFuncAttributeMaxDynamicSharedMemorySize, SMEM_SZ);
  float* state_out = out + (size_t)L_DIM * B_DIM * H_DIM;  // 33554432
  fused_scan<<<48, 256, SMEM_SZ, stream>>>(xpH, Whh0h, Wih1h, Whh1h, b1, state,
                                           h0slots, h1buf, flags0, flags1,
                                           out, state_out);
}

// Round 11
// 3681.663 us; speedup vs baseline: 5.7535x; 1.0000x over previous
//
#include <hip/hip_runtime.h>
#include <hip/hip_bf16.h>

typedef _Float16 f16_t;
using f16x8  = __attribute__((ext_vector_type(8))) _Float16;
using f32x4  = __attribute__((ext_vector_type(4))) float;
using f32x16 = __attribute__((ext_vector_type(16))) float;
using u64    = unsigned long long;
using u64x2  = __attribute__((ext_vector_type(2))) unsigned long long;

#define L_DIM 512
#define B_DIM 64
#define C_DIM 512
#define H_DIM 1024
#define MROWS (L_DIM * B_DIM) /* 32768 */
#define SLOT_SZ 131072        /* one full h state in fragment layout */

// ---------------- f32 -> f16 convert ----------------
__global__ void cvt_kernel(const float* __restrict__ src, f16_t* __restrict__ dst, int n8) {
  int i = blockIdx.x * blockDim.x + threadIdx.x;
  if (i >= n8) return;
  const float4* s4 = reinterpret_cast<const float4*>(src) + (size_t)i * 2;
  float4 a = s4[0], b = s4[1];
  f16x8 o;
  o[0] = (f16_t)a.x; o[1] = (f16_t)a.y; o[2] = (f16_t)a.z; o[3] = (f16_t)a.w;
  o[4] = (f16_t)b.x; o[5] = (f16_t)b.y; o[6] = (f16_t)b.z; o[7] = (f16_t)b.w;
  reinterpret_cast<f16x8*>(dst)[i] = o;
}

// ---------------- async global->LDS 16B ----------------
__device__ inline void gload_lds16(const void* g, void* l) {
  __builtin_amdgcn_global_load_lds(
      (const __attribute__((address_space(1))) unsigned int*)g,
      (__attribute__((address_space(3))) unsigned int*)l, 16, 0, 0);
}

// ---------------- bt-GEMM: C[M,N] = A[M,K] @ B[N,K]^T + bias, f16 out ----------------
#define TM 128
#define TN 128
#define BKK 64
__global__ __launch_bounds__(256) void gemm_bt_bias(
    const f16_t* __restrict__ A, const f16_t* __restrict__ B,
    const float* __restrict__ bias, f16_t* __restrict__ C,
    int M, int N, int K) {
  __shared__ f16_t As[TM * BKK];
  __shared__ f16_t Bs[TN * BKK];
  const int tid = threadIdx.x;
  const int w = tid >> 6, l = tid & 63;
  const int nbn = N / TN;
  const int bm = blockIdx.x / nbn, bn = blockIdx.x % nbn;
  const int m0 = bm * TM, n0 = bn * TN;
  const int wr = w >> 1, wc = w & 1;
  const int lr = l & 15;
  const int lk = (l >> 4) * 8;
  f32x4 acc[4][4] = {};

  for (int kt = 0; kt < K; kt += BKK) {
#pragma unroll
    for (int r = 0; r < 4; ++r) {
      int p8 = r * 256 + tid;
      int row = p8 >> 3, col = (p8 & 7) * 8;
      gload_lds16(A + (size_t)(m0 + row) * K + kt + col, &As[(size_t)(r * 256 + w * 64) * 8]);
    }
#pragma unroll
    for (int r = 0; r < 4; ++r) {
      int p8 = r * 256 + tid;
      int row = p8 >> 3, col = (p8 & 7) * 8;
      gload_lds16(B + (size_t)(n0 + row) * K + kt + col, &Bs[(size_t)(r * 256 + w * 64) * 8]);
    }
    __syncthreads();
#pragma unroll
    for (int kk = 0; kk < 2; ++kk) {
      f16x8 af[4], bfr[4];
#pragma unroll
      for (int i = 0; i < 4; ++i)
        af[i] = *reinterpret_cast<const f16x8*>(&As[(wr * 64 + i * 16 + lr) * BKK + kk * 32 + lk]);
#pragma unroll
      for (int j = 0; j < 4; ++j)
        bfr[j] = *reinterpret_cast<const f16x8*>(&Bs[(wc * 64 + j * 16 + lr) * BKK + kk * 32 + lk]);
#pragma unroll
      for (int i = 0; i < 4; ++i)
#pragma unroll
        for (int j = 0; j < 4; ++j)
          acc[i][j] = __builtin_amdgcn_mfma_f32_16x16x32_f16(af[i], bfr[j], acc[i][j], 0, 0, 0);
    }
    __syncthreads();
  }
  const int crow = (l >> 4) * 4, ccol = l & 15;
#pragma unroll
  for (int j = 0; j < 4; ++j) {
    int col = n0 + wc * 64 + j * 16 + ccol;
    float bv = bias[col];
#pragma unroll
    for (int i = 0; i < 4; ++i) {
      int rowb = m0 + wr * 64 + i * 16 + crow;
#pragma unroll
      for (int r = 0; r < 4; ++r)
        C[(size_t)(rowb + r) * N + col] = (f16_t)(acc[i][j][r] + bv);
    }
  }
}

// 16B L3-coherent load/store (validated r5-r9 protocol)
#define GLOAD16(dst, addr) \
  asm volatile("global_load_dwordx4 %0, %1, off sc0 sc1" : "=&v"(dst) : "v"(addr) : "memory")
#define GSTORE16(addr, val) \
  asm volatile("global_store_dwordx4 %0, %1, off sc0 sc1" :: "v"(addr), "v"(val) : "memory")
#define WAITV(n) do { asm volatile("s_waitcnt vmcnt(" #n ")" ::: "memory"); \
                      __builtin_amdgcn_sched_barrier(0); } while (0)

// LDS maps. Layer0: [0,128K) W; [128K,144K) RED; [144K,152K) pk(128B rows)
// Layer1: [0,64K) Wih; [64K,128K) Whh; [128K,136K) RED; [136K,140K) pk(64B rows)
#define RED_OFF  131072
#define PK_OFF   147456
#define L1_RED   131072
#define L1_PK    139264
#define SMEM_SZ  155648

// ---------------- fused 2-layer pipelined scan (r9-validated) ----------------
// Blocks 0..15: layer0, cols [g*64,+64). h0 published per-step to write-once
//   slots (513 x 128KB). Barrier group: flags0[16]. L0 ALWAYS publishes
//   flags0=t+2 (incl. final t=511 -> 513) so L1 can drain.
// Blocks 16..47: layer1, cols [g1*32,+32), one step behind. Consumes h0 slot
//   t+1 (ready when flags0>=t+2) + own h1 ping-pong (flags1[32]).
__global__ __launch_bounds__(256, 1) void fused_scan(
    const f16_t* __restrict__ xpH,    // [512][64][1024] f16 (layer0 input proj)
    const f16_t* __restrict__ Whh0,   // [1024][1024] f16
    const f16_t* __restrict__ Wih1,   // [1024][1024] f16
    const f16_t* __restrict__ Whh1,   // [1024][1024] f16
    const float* __restrict__ b1,     // [1024]
    const float* __restrict__ state_in, // [2][64][1024] f32
    char* __restrict__ h0slots,       // 513 x SLOT_SZ fragment slots
    char* __restrict__ h1buf,         // 2 x SLOT_SZ ping-pong
    unsigned* __restrict__ flags0,    // 16
    unsigned* __restrict__ flags1,    // 32
    float* __restrict__ out,          // [512][64][1024] f32 (layer1 seq)
    float* __restrict__ state_out) {  // [2][64][1024] f32
  extern __shared__ char smem[];
  const int tid = threadIdx.x;
  const int w = tid >> 6, l = tid & 63;
  const int wr = w >> 1, kh = w & 1;
  const int la = l & 31, lb = l >> 5;

  if (blockIdx.x < 16) {
    // ================= LAYER 0 =================
    char* pkc = smem + PK_OFF;
    const int g = blockIdx.x;
    const int n0 = g * 64;
    for (int i = 0; i < 32; ++i) {
      int g8 = i * 256 + tid;
      int row = g8 >> 7, cb = g8 & 127;
      f16x8 v = *reinterpret_cast<const f16x8*>(Whh0 + (size_t)(n0 + row) * H_DIM + cb * 8);
      *reinterpret_cast<f16x8*>(smem + row * 2048 + ((cb ^ (row & 31)) << 4)) = v;
    }
#pragma unroll
    for (int i = 0; i < 2; ++i) {
      int f = tid * 2 + i;
      int kbl = f >> 7, rem = f & 127, rh = rem >> 6, lf = rem & 63;
      int row = rh * 32 + (lf & 31);
      int cgl = (4 * g + kbl) * 16 + (lf >> 5) * 8;
      const float* s = state_in + row * H_DIM + cgl;
      float4 a = *reinterpret_cast<const float4*>(s);
      float4 b = *reinterpret_cast<const float4*>(s + 4);
      f16x8 v;
      v[0] = (f16_t)a.x; v[1] = (f16_t)a.y; v[2] = (f16_t)a.z; v[3] = (f16_t)a.w;
      v[4] = (f16_t)b.x; v[5] = (f16_t)b.y; v[6] = (f16_t)b.z; v[7] = (f16_t)b.w;
      GSTORE16(h0slots + g * 8192 + f * 16, v);
    }
    asm volatile("s_waitcnt vmcnt(0)" ::: "memory");
    __syncthreads();
    if (tid < 64) {
      if (tid == 0)
        __hip_atomic_store(&flags0[g], 1u, __ATOMIC_RELAXED, __HIP_MEMORY_SCOPE_AGENT);
      int src = tid & 15;
      unsigned v;
      do { v = __hip_atomic_load(&flags0[src], __ATOMIC_RELAXED, __HIP_MEMORY_SCOPE_AGENT);
      } while (!__all((int)(v >= 1u)));
    }
    __syncthreads();

    const char* smem_w0 = smem + la * 2048;
    const char* smem_w1 = smem + (32 + la) * 2048;
    const int rx = la;
    const int colg = n0 + kh * 32 + la;
    const int pcg = (kh * 32 + la) >> 3;
    const int pco = ((kh * 32 + la) & 7) * 2;

#define MFMA_HALF(bufarr, base)                                                \
  _Pragma("unroll")                                                            \
  for (int i_ = 0; i_ < 16; ++i_) {                                            \
    int cb_ = ((((base) + i_) * 2 + lb) ^ rx) << 4;                            \
    f16x8 a_ = __builtin_bit_cast(f16x8, bufarr[i_]);                          \
    f16x8 b0_ = *reinterpret_cast<const f16x8*>(smem_w0 + cb_);                \
    f16x8 b1_ = *reinterpret_cast<const f16x8*>(smem_w1 + cb_);                \
    acc0 = __builtin_amdgcn_mfma_f32_32x32x16_f16(a_, b0_, acc0, 0, 0, 0);     \
    acc1 = __builtin_amdgcn_mfma_f32_32x32x16_f16(a_, b1_, acc1, 0, 0, 0);     \
  }

    for (int t = 0; t < 512; ++t) {
      const char* hb = h0slots + (size_t)t * SLOT_SZ + wr * 1024 + l * 16;
      char* hd = h0slots + (size_t)(t + 1) * SLOT_SZ + g * 8192;
      u64x2 bf0[16], bf1[16];
#pragma unroll
      for (int i = 0; i < 16; ++i) GLOAD16(bf0[i], hb + (kh * 32 + i) * 2048);
#pragma unroll
      for (int i = 0; i < 16; ++i) GLOAD16(bf1[i], hb + (kh * 32 + 16 + i) * 2048);
      float xv[16];
#pragma unroll
      for (int r = 0; r < 16; ++r) {
        int row = wr * 32 + (r & 3) + 8 * (r >> 2) + 4 * lb;
        xv[r] = (float)xpH[(size_t)t * 65536 + row * H_DIM + colg];
      }
      f32x16 acc0 = {}, acc1 = {};
      WAITV(32);
      MFMA_HALF(bf0, kh * 32);
      WAITV(16);
      MFMA_HALF(bf1, kh * 32 + 16);
      WAITV(0);
      {
        f32x16 oth = kh ? acc0 : acc1;
        char* rw = smem + RED_OFF + (size_t)(wr * 2 + (kh ^ 1)) * 4096;
#pragma unroll
        for (int i4 = 0; i4 < 4; ++i4) {
          f32x4 q = {oth[i4 * 4], oth[i4 * 4 + 1], oth[i4 * 4 + 2], oth[i4 * 4 + 3]};
          *reinterpret_cast<f32x4*>(rw + i4 * 1024 + l * 16) = q;
        }
      }
      __syncthreads();
      f32x16 mine = kh ? acc1 : acc0;
      {
        const char* rr = smem + RED_OFF + (size_t)(wr * 2 + kh) * 4096;
#pragma unroll
        for (int i4 = 0; i4 < 4; ++i4) {
          f32x4 q = *reinterpret_cast<const f32x4*>(rr + i4 * 1024 + l * 16);
          mine[i4 * 4] += q[0]; mine[i4 * 4 + 1] += q[1];
          mine[i4 * 4 + 2] += q[2]; mine[i4 * 4 + 3] += q[3];
        }
      }
      const bool wlast = (t == 511);
#pragma unroll
      for (int r = 0; r < 16; ++r) {
        int row = wr * 32 + (r & 3) + 8 * (r >> 2) + 4 * lb;
        float z = mine[r] + xv[r];
        z = fminf(fmaxf(z, -15.f), 15.f);
        float e = __expf(2.f * z);
        float h = 1.f - __fdividef(2.f, e + 1.f);
        f16_t hf = (f16_t)h;
        *reinterpret_cast<unsigned short*>(
            pkc + row * 128 + ((pcg ^ (row & 7)) << 4) + pco) =
            __builtin_bit_cast(unsigned short, hf);
        if (wlast) state_out[row * H_DIM + colg] = (float)hf;
      }
      __syncthreads();
#pragma unroll
      for (int i = 0; i < 2; ++i) {
        int f = tid * 2 + i;
        int kbl = f >> 7, rem = f & 127, rh = rem >> 6, lf = rem & 63;
        int row = rh * 32 + (lf & 31);
        int cg = kbl * 2 + (lf >> 5);
        u64x2 q = *reinterpret_cast<const u64x2*>(pkc + row * 128 + ((cg ^ (row & 7)) << 4));
        GSTORE16(hd + f * 16, q);
      }
      asm volatile("s_waitcnt vmcnt(0) lgkmcnt(0)" ::: "memory");
      __builtin_amdgcn_sched_barrier(0);
      // ALWAYS publish: L1 waits for flags0 up to 513.
      __builtin_amdgcn_s_barrier();
      unsigned target = (unsigned)(t + 2);
      if (tid == 0)
        __hip_atomic_store(&flags0[g], target, __ATOMIC_RELAXED, __HIP_MEMORY_SCOPE_AGENT);
      if (!wlast) {
        if (tid < 64) {
          int src = tid & 15;
          unsigned v;
          do { v = __hip_atomic_load(&flags0[src], __ATOMIC_RELAXED, __HIP_MEMORY_SCOPE_AGENT);
          } while (!__all((int)(v >= target)));
        }
        __builtin_amdgcn_s_barrier();
      }
    }
#undef MFMA_HALF
  } else {
    // ================= LAYER 1 =================
    char* pk1 = smem + L1_PK;
    const int g1 = blockIdx.x - 16;
    const int n1 = g1 * 32;
    for (int i = 0; i < 16; ++i) {
      int g8 = i * 256 + tid;
      int row = g8 >> 7, cb = g8 & 127;
      f16x8 v = *reinterpret_cast<const f16x8*>(Wih1 + (size_t)(n1 + row) * H_DIM + cb * 8);
      *reinterpret_cast<f16x8*>(smem + row * 2048 + ((cb ^ row) << 4)) = v;
    }
    for (int i = 0; i < 16; ++i) {
      int g8 = i * 256 + tid;
      int row = g8 >> 7, cb = g8 & 127;
      f16x8 v = *reinterpret_cast<const f16x8*>(Whh1 + (size_t)(n1 + row) * H_DIM + cb * 8);
      *reinterpret_cast<f16x8*>(smem + 65536 + row * 2048 + ((cb ^ row) << 4)) = v;
    }
    {
      int kbl = tid >> 7, rem = tid & 127, rh = rem >> 6, lf = rem & 63;
      int row = rh * 32 + (lf & 31);
      int cgl = (2 * g1 + kbl) * 16 + (lf >> 5) * 8;
      const float* s = state_in + 65536 + row * H_DIM + cgl;
      float4 a = *reinterpret_cast<const float4*>(s);
      float4 b = *reinterpret_cast<const float4*>(s + 4);
      f16x8 v;
      v[0] = (f16_t)a.x; v[1] = (f16_t)a.y; v[2] = (f16_t)a.z; v[3] = (f16_t)a.w;
      v[4] = (f16_t)b.x; v[5] = (f16_t)b.y; v[6] = (f16_t)b.z; v[7] = (f16_t)b.w;
      GSTORE16(h1buf + (2 * g1 + kbl) * 2048 + rh * 1024 + lf * 16, v);
    }
    asm volatile("s_waitcnt vmcnt(0)" ::: "memory");
    __syncthreads();
    if (tid < 64) {
      if (tid == 0)
        __hip_atomic_store(&flags1[g1], 1u, __ATOMIC_RELAXED, __HIP_MEMORY_SCOPE_AGENT);
      const unsigned* src = (tid < 16) ? &flags0[tid] : &flags1[(tid - 16) & 31];
      unsigned tgt = (tid < 16) ? 2u : 1u;
      unsigned v;
      do { v = __hip_atomic_load(src, __ATOMIC_RELAXED, __HIP_MEMORY_SCOPE_AGENT);
      } while (!__all((int)(v >= tgt)));
    }
    __syncthreads();

    const char* wih_base = smem + la * 2048;
    const char* whh_base = smem + 65536 + la * 2048;
    const int rx = la;
    const float bv1 = b1[n1 + la];
    const int pcg1 = la >> 3, pco1 = (la & 7) * 2;

#define MFMA16_L1(bufarr, wbase, kbase)                                        \
  _Pragma("unroll")                                                            \
  for (int i_ = 0; i_ < 16; ++i_) {                                            \
    int cb_ = ((((kbase) + i_) * 2 + lb) ^ rx) << 4;                           \
    f16x8 a_ = __builtin_bit_cast(f16x8, bufarr[i_]);                          \
    f16x8 b_ = *reinterpret_cast<const f16x8*>((wbase) + cb_);                 \
    if (i_ & 1) accB = __builtin_amdgcn_mfma_f32_32x32x16_f16(a_, b_, accB, 0, 0, 0); \
    else        accA = __builtin_amdgcn_mfma_f32_32x32x16_f16(a_, b_, accA, 0, 0, 0); \
  }

    for (int t = 0; t < 512; ++t) {
      const char* hb0 = h0slots + (size_t)(t + 1) * SLOT_SZ + wr * 1024 + l * 16;
      const char* hb1 = h1buf + (size_t)(t & 1) * SLOT_SZ + wr * 1024 + l * 16;
      char* h1d = h1buf + (size_t)((t + 1) & 1) * SLOT_SZ;
      u64x2 bf0[16], bf1[16];
#pragma unroll
      for (int i = 0; i < 16; ++i) GLOAD16(bf0[i], hb0 + (kh * 32 + i) * 2048);
#pragma unroll
      for (int i = 0; i < 16; ++i) GLOAD16(bf1[i], hb0 + (kh * 32 + 16 + i) * 2048);
      f32x16 accA = {}, accB = {};
      WAITV(16);                     // prev outs (<=2) + c0
      MFMA16_L1(bf0, wih_base, kh * 32);
#pragma unroll
      for (int i = 0; i < 16; ++i) GLOAD16(bf0[i], hb1 + (kh * 32 + i) * 2048);
      WAITV(16);                     // c1
      MFMA16_L1(bf1, wih_base, kh * 32 + 16);
#pragma unroll
      for (int i = 0; i < 16; ++i) GLOAD16(bf1[i], hb1 + (kh * 32 + 16 + i) * 2048);
      WAITV(16);                     // c2
      MFMA16_L1(bf0, whh_base, kh * 32);
      WAITV(0);                      // c3
      MFMA16_L1(bf1, whh_base, kh * 32 + 16);

      if (kh) {
        char* rw = smem + L1_RED + wr * 4096;
#pragma unroll
        for (int i4 = 0; i4 < 4; ++i4) {
          f32x4 q = {accA[i4 * 4] + accB[i4 * 4],
                     accA[i4 * 4 + 1] + accB[i4 * 4 + 1],
                     accA[i4 * 4 + 2] + accB[i4 * 4 + 2],
                     accA[i4 * 4 + 3] + accB[i4 * 4 + 3]};
          *reinterpret_cast<f32x4*>(rw + i4 * 1024 + l * 16) = q;
        }
      }
      __syncthreads();
      const bool wlast = (t == 511);
      if (!kh) {
        const char* rr = smem + L1_RED + wr * 4096;
        float rd[16];
#pragma unroll
        for (int i4 = 0; i4 < 4; ++i4) {
          f32x4 q = *reinterpret_cast<const f32x4*>(rr + i4 * 1024 + l * 16);
          rd[i4 * 4] = q[0]; rd[i4 * 4 + 1] = q[1];
          rd[i4 * 4 + 2] = q[2]; rd[i4 * 4 + 3] = q[3];
        }
#pragma unroll
        for (int r = 0; r < 16; ++r) {
          int row = wr * 32 + (r & 3) + 8 * (r >> 2) + 4 * lb;
          float z = accA[r] + accB[r] + rd[r] + bv1;
          z = fminf(fmaxf(z, -15.f), 15.f);
          float e = __expf(2.f * z);
          float h = 1.f - __fdividef(2.f, e + 1.f);
          f16_t hf = (f16_t)h;
          *reinterpret_cast<unsigned short*>(
              pk1 + row * 64 + ((pcg1 ^ (row & 3)) << 4) + pco1) =
              __builtin_bit_cast(unsigned short, hf);
          if (wlast) state_out[65536 + row * H_DIM + n1 + la] = (float)hf;
        }
      }
      __syncthreads();
      {
        int kbl = tid >> 7, rem = tid & 127, rh = rem >> 6, lf = rem & 63;
        int row = rh * 32 + (lf & 31);
        int cg = kbl * 2 + (lf >> 5);
        u64x2 q = *reinterpret_cast<const u64x2*>(pk1 + row * 64 + ((cg ^ (row & 3)) << 4));
        GSTORE16(h1d + (2 * g1 + kbl) * 2048 + rh * 1024 + lf * 16, q);
      }
      {
        int srow = tid >> 2, cg0 = tid & 3;
        u64x2 q = *reinterpret_cast<const u64x2*>(pk1 + srow * 64 + ((cg0 ^ (srow & 3)) << 4));
        f16x8 a0 = __builtin_bit_cast(f16x8, q);
        float4 f0 = {(float)a0[0], (float)a0[1], (float)a0[2], (float)a0[3]};
        float4 f1 = {(float)a0[4], (float)a0[5], (float)a0[6], (float)a0[7]};
        char* oa = (char*)out + (size_t)t * 262144 + srow * 4096 + (n1 + cg0 * 8) * 4;
        *reinterpret_cast<float4*>(oa) = f0;
        *reinterpret_cast<float4*>(oa + 16) = f1;
      }
      asm volatile("s_waitcnt vmcnt(2) lgkmcnt(0)" ::: "memory");
      __builtin_amdgcn_sched_barrier(0);
      if (!wlast) {
        __builtin_amdgcn_s_barrier();
        unsigned t1t = (unsigned)(t + 2), t0t = (unsigned)(t + 3);
        if (tid < 64) {
          if (tid == 0)
            __hip_atomic_store(&flags1[g1], t1t, __ATOMIC_RELAXED, __HIP_MEMORY_SCOPE_AGENT);
          const unsigned* src = (tid < 16) ? &flags0[tid] : &flags1[(tid - 16) & 31];
          unsigned tgt = (tid < 16) ? t0t : t1t;
          unsigned v;
          do { v = __hip_atomic_load(src, __ATOMIC_RELAXED, __HIP_MEMORY_SCOPE_AGENT);
          } while (!__all((int)(v >= tgt)));
        }
        __builtin_amdgcn_s_barrier();
      }
    }
#undef MFMA16_L1
  }
}

extern "C" void kernel_launch(void* const* d_in, const int* in_sizes, int n_in,
                              void* d_out, int out_size, void* d_ws, size_t ws_size,
                              hipStream_t stream) {
  const float* x     = (const float*)d_in[0];
  const float* state = (const float*)d_in[1];
  const float* Wih0  = (const float*)d_in[2];
  const float* Whh0  = (const float*)d_in[3];
  const float* b0    = (const float*)d_in[4];
  const float* Wih1  = (const float*)d_in[5];
  const float* Whh1  = (const float*)d_in[6];
  const float* b1    = (const float*)d_in[7];
  float* out = (float*)d_out;

  char* ws = (char*)d_ws;
  unsigned* flags0 = (unsigned*)(ws + 0);              // 16
  unsigned* flags1 = (unsigned*)(ws + 1024);           // 32
  char*  h1buf    = ws + 4096;                         // 256 KiB
  char*  h0slots  = ws + 266240;                       // 513 x 128 KiB = 64.1 MiB
  f16_t* Whh0h    = (f16_t*)(ws + 67506176);           // 2 MiB
  f16_t* Wih1h    = (f16_t*)(ws + 69603328);           // 2 MiB
  f16_t* Whh1h    = (f16_t*)(ws + 71700480);           // 2 MiB
  f16_t* Wih0h    = (f16_t*)(ws + 73797632);           // 1 MiB
  f16_t* xh       = (f16_t*)(ws + 74846208);           // 32 MiB
  f16_t* xpH      = (f16_t*)(ws + 108400640);          // 64 MiB f16 xp

  hipMemsetAsync(ws, 0, 4096, stream);
  cvt_kernel<<<8192, 256, 0, stream>>>(x,    xh,    16777216 / 8);
  cvt_kernel<<<256,  256, 0, stream>>>(Wih0, Wih0h,   524288 / 8);
  cvt_kernel<<<512,  256, 0, stream>>>(Whh0, Whh0h,  1048576 / 8);
  cvt_kernel<<<512,  256, 0, stream>>>(Wih1, Wih1h,  1048576 / 8);
  cvt_kernel<<<512,  256, 0, stream>>>(Whh1, Whh1h,  1048576 / 8);

  // layer 0 input projection: [32768,512] @ [1024,512]^T -> f16 xp
  gemm_bt_bias<<<dim3((MROWS / TM) * (H_DIM / TN)), 256, 0, stream>>>(
      xh, Wih0h, b0, xpH, MROWS, H_DIM, C_DIM);

  (void)hipFuncSetAttribute((const void*)fused_scan,
                            hipFuncAttributeMaxDynamicSharedMemorySize, SMEM_SZ);
  float* state_out = out + (size_t)L_DIM * B_DIM * H_DIM;  // 33554432
  fused_scan<<<48, 256, SMEM_SZ, stream>>>(xpH, Whh0h, Wih1h, Whh1h, b1, state,
                                           h0slots, h1buf, flags0, flags1,
                                           out, state_out);
}